// Round 1
// baseline (2481.358 us; speedup 1.0000x reference)
//
#include <hip/hip_runtime.h>
#include <hip/hip_bf16.h>

#define B_  4
#define T_  2048
#define C_  1024
#define H_  16
#define D_  64
#define C3_ 3072

// ---------------------------------------------------------------------------
// Generic fp32 GEMM with bias: C[M,N] = A[M,K] @ B[K,N] + bias[N]
// 128x128 tile, BK=8, 256 threads, 8x8 micro-tile per thread.
// ---------------------------------------------------------------------------
__global__ __launch_bounds__(256)
void sgemm_bias(const float* __restrict__ A, const float* __restrict__ Bm,
                const float* __restrict__ bias, float* __restrict__ Cm,
                int M, int N, int K) {
  __shared__ float As[8][128];   // transposed: As[k][m]
  __shared__ float Bs[8][128];   // Bs[k][n]

  const int tid = threadIdx.x;
  const int tx = tid & 15;       // 0..15 -> col group
  const int ty = tid >> 4;       // 0..15 -> row group
  const int row0 = blockIdx.y * 128;
  const int col0 = blockIdx.x * 128;

  float acc[8][8];
#pragma unroll
  for (int i = 0; i < 8; ++i)
#pragma unroll
    for (int j = 0; j < 8; ++j) acc[i][j] = 0.0f;

  // A-tile load mapping: 128 rows x 8 k = 1024 floats = 256 threads x float4
  const int arow = tid >> 1;          // 0..127
  const int acol = (tid & 1) * 4;     // 0 or 4
  // B-tile load mapping: 8 rows x 128 cols
  const int brow = tid >> 5;          // 0..7
  const int bcol = (tid & 31) * 4;    // 0..124

  for (int k0 = 0; k0 < K; k0 += 8) {
    float4 a4 = *(const float4*)&A[(size_t)(row0 + arow) * K + k0 + acol];
    float4 b4 = *(const float4*)&Bm[(size_t)(k0 + brow) * N + col0 + bcol];
    As[acol + 0][arow] = a4.x;
    As[acol + 1][arow] = a4.y;
    As[acol + 2][arow] = a4.z;
    As[acol + 3][arow] = a4.w;
    *(float4*)&Bs[brow][bcol] = b4;
    __syncthreads();

#pragma unroll
    for (int k = 0; k < 8; ++k) {
      float a[8], b[8];
      *(float4*)&a[0] = *(const float4*)&As[k][ty * 8];
      *(float4*)&a[4] = *(const float4*)&As[k][ty * 8 + 4];
      *(float4*)&b[0] = *(const float4*)&Bs[k][tx * 8];
      *(float4*)&b[4] = *(const float4*)&Bs[k][tx * 8 + 4];
#pragma unroll
      for (int i = 0; i < 8; ++i)
#pragma unroll
        for (int j = 0; j < 8; ++j)
          acc[i][j] = fmaf(a[i], b[j], acc[i][j]);
    }
    __syncthreads();
  }

#pragma unroll
  for (int i = 0; i < 8; ++i) {
    const int r = row0 + ty * 8 + i;
#pragma unroll
    for (int j = 0; j < 8; j += 4) {
      const int c = col0 + tx * 8 + j;
      float4 o;
      o.x = acc[i][j + 0] + bias[c + 0];
      o.y = acc[i][j + 1] + bias[c + 1];
      o.z = acc[i][j + 2] + bias[c + 2];
      o.w = acc[i][j + 3] + bias[c + 3];
      *(float4*)&Cm[(size_t)r * N + c] = o;
    }
  }
}

// ---------------------------------------------------------------------------
// Flash-style causal attention, fp32.
// grid = (T/64, H, B), block = 256 (4 waves).
// Each block: one 64-row q-tile of one (b,h). Streams 64-row K/V tiles.
// LDS row stride 76 floats (76%32=12) to avoid 8-way bank conflicts.
// ---------------------------------------------------------------------------
#define LDST 76

__global__ __launch_bounds__(256)
void attn_fwd(const float* __restrict__ qkv, float* __restrict__ y) {
  __shared__ float Qs[64][LDST];
  __shared__ float Ks[64][LDST];
  __shared__ float Vs[64][LDST];
  __shared__ float Ss[64][LDST];
  __shared__ float m_s[64], l_s[64], alpha_s[64];

  const int qt = blockIdx.x;   // q-tile index 0..31
  const int h  = blockIdx.y;
  const int b  = blockIdx.z;
  const int tid = threadIdx.x;
  const int tx = tid & 15;
  const int ty = tid >> 4;
  const int r0 = ty * 4;       // 4 q-rows owned in compute phases
  const int c0 = tx * 4;       // 4 cols owned
  const float scale = 0.125f;  // 1/sqrt(64)

  const float* qbase = qkv + (size_t)b * T_ * C3_ + (size_t)h * D_;
  const float* kbase = qbase + C_;
  const float* vbase = qbase + 2 * C_;

  // Load Q tile (64x64): 1024 float4s over 256 threads x 4
#pragma unroll
  for (int i = 0; i < 4; ++i) {
    int e = tid + i * 256;
    int r = e >> 4, d4 = (e & 15) * 4;
    *(float4*)&Qs[r][d4] =
        *(const float4*)&qbase[(size_t)(qt * 64 + r) * C3_ + d4];
  }
  if (tid < 64) { m_s[tid] = -1e30f; l_s[tid] = 0.0f; }

  float Oacc[4][4];
#pragma unroll
  for (int i = 0; i < 4; ++i)
#pragma unroll
    for (int j = 0; j < 4; ++j) Oacc[i][j] = 0.0f;

  for (int j = 0; j <= qt; ++j) {
    __syncthreads();   // previous PV done (and Q/m/l init visible)
#pragma unroll
    for (int i = 0; i < 4; ++i) {
      int e = tid + i * 256;
      int r = e >> 4, d4 = (e & 15) * 4;
      *(float4*)&Ks[r][d4] =
          *(const float4*)&kbase[(size_t)(j * 64 + r) * C3_ + d4];
      *(float4*)&Vs[r][d4] =
          *(const float4*)&vbase[(size_t)(j * 64 + r) * C3_ + d4];
    }
    __syncthreads();

    // ---- S = scale * Q K^T  (64x64x64), 4x4 per thread ----
    float s[4][4];
#pragma unroll
    for (int i = 0; i < 4; ++i)
#pragma unroll
      for (int jj = 0; jj < 4; ++jj) s[i][jj] = 0.0f;

    for (int d0 = 0; d0 < 64; d0 += 4) {
      float4 q4[4], k4[4];
#pragma unroll
      for (int i = 0; i < 4; ++i) q4[i] = *(const float4*)&Qs[r0 + i][d0];
#pragma unroll
      for (int jj = 0; jj < 4; ++jj) k4[jj] = *(const float4*)&Ks[c0 + jj][d0];
#pragma unroll
      for (int i = 0; i < 4; ++i)
#pragma unroll
        for (int jj = 0; jj < 4; ++jj)
          s[i][jj] += q4[i].x * k4[jj].x + q4[i].y * k4[jj].y +
                      q4[i].z * k4[jj].z + q4[i].w * k4[jj].w;
    }

    const bool diag = (j == qt);
#pragma unroll
    for (int i = 0; i < 4; ++i)
#pragma unroll
      for (int jj = 0; jj < 4; ++jj) {
        float val = s[i][jj] * scale;
        if (diag && (c0 + jj) > (r0 + i)) val = -1e30f;  // causal mask
        Ss[r0 + i][c0 + jj] = val;
      }
    __syncthreads();

    // ---- online softmax: 4 lanes per row ----
    {
      const int row = tid >> 2, quad = tid & 3;
      float sv[16];
      float mloc = -1e30f;
#pragma unroll
      for (int c = 0; c < 16; ++c) {
        sv[c] = Ss[row][quad * 16 + c];
        mloc = fmaxf(mloc, sv[c]);
      }
      mloc = fmaxf(mloc, __shfl_xor(mloc, 1));
      mloc = fmaxf(mloc, __shfl_xor(mloc, 2));
      const float m_old = m_s[row];
      const float m_new = fmaxf(m_old, mloc);
      float lsum = 0.0f;
#pragma unroll
      for (int c = 0; c < 16; ++c) {
        float p = __expf(sv[c] - m_new);
        Ss[row][quad * 16 + c] = p;
        lsum += p;
      }
      lsum += __shfl_xor(lsum, 1);
      lsum += __shfl_xor(lsum, 2);
      if (quad == 0) {
        const float alpha = __expf(m_old - m_new);
        l_s[row] = l_s[row] * alpha + lsum;
        m_s[row] = m_new;
        alpha_s[row] = alpha;
      }
    }
    __syncthreads();

    // ---- O = O*alpha + P V  (64x64x64), 4x4 per thread ----
    float alr[4];
#pragma unroll
    for (int i = 0; i < 4; ++i) alr[i] = alpha_s[r0 + i];
#pragma unroll
    for (int i = 0; i < 4; ++i)
#pragma unroll
      for (int jj = 0; jj < 4; ++jj) Oacc[i][jj] *= alr[i];

    for (int k0 = 0; k0 < 64; k0 += 4) {
      float4 p4[4], v4[4];
#pragma unroll
      for (int i = 0; i < 4; ++i) p4[i] = *(const float4*)&Ss[r0 + i][k0];
#pragma unroll
      for (int l = 0; l < 4; ++l) v4[l] = *(const float4*)&Vs[k0 + l][c0];
#pragma unroll
      for (int i = 0; i < 4; ++i) {
        Oacc[i][0] += p4[i].x * v4[0].x + p4[i].y * v4[1].x +
                      p4[i].z * v4[2].x + p4[i].w * v4[3].x;
        Oacc[i][1] += p4[i].x * v4[0].y + p4[i].y * v4[1].y +
                      p4[i].z * v4[2].y + p4[i].w * v4[3].y;
        Oacc[i][2] += p4[i].x * v4[0].z + p4[i].y * v4[1].z +
                      p4[i].z * v4[2].z + p4[i].w * v4[3].z;
        Oacc[i][3] += p4[i].x * v4[0].w + p4[i].y * v4[1].w +
                      p4[i].z * v4[2].w + p4[i].w * v4[3].w;
      }
    }
  }

  // epilogue: O /= l, write y[b,t,h*64+d]  (y laid out [B*T, C])
  float linv[4];
#pragma unroll
  for (int i = 0; i < 4; ++i) linv[i] = 1.0f / l_s[r0 + i];
  float* yb = y + ((size_t)b * T_ + (size_t)qt * 64) * C_ + h * D_;
#pragma unroll
  for (int i = 0; i < 4; ++i) {
    float4 o;
    o.x = Oacc[i][0] * linv[i];
    o.y = Oacc[i][1] * linv[i];
    o.z = Oacc[i][2] * linv[i];
    o.w = Oacc[i][3] * linv[i];
    *(float4*)&yb[(size_t)(r0 + i) * C_ + c0] = o;
  }
}

// ---------------------------------------------------------------------------
extern "C" void kernel_launch(void* const* d_in, const int* in_sizes, int n_in,
                              void* d_out, int out_size, void* d_ws, size_t ws_size,
                              hipStream_t stream) {
  const float* x      = (const float*)d_in[0];  // [B,T,C]
  const float* w_attn = (const float*)d_in[1];  // [C,3C]
  const float* b_attn = (const float*)d_in[2];  // [3C]
  const float* w_proj = (const float*)d_in[3];  // [C,C]
  const float* b_proj = (const float*)d_in[4];  // [C]
  float* out = (float*)d_out;                   // [B,T,C]

  float* qkv = (float*)d_ws;                       // [B*T, 3C] = 96 MB
  float* y   = qkv + (size_t)(B_ * T_) * C3_;      // [B*T, C]  = 32 MB

  // 1) qkv = x @ w_attn + b_attn
  dim3 g1(C3_ / 128, (B_ * T_) / 128);
  sgemm_bias<<<g1, 256, 0, stream>>>(x, w_attn, b_attn, qkv,
                                     B_ * T_, C3_, C_);

  // 2) flash attention per (b, h, q-tile)
  dim3 g2(T_ / 64, H_, B_);
  attn_fwd<<<g2, 256, 0, stream>>>(qkv, y);

  // 3) out = y @ w_proj + b_proj
  dim3 g3(C_ / 128, (B_ * T_) / 128);
  sgemm_bias<<<g3, 256, 0, stream>>>(y, w_proj, b_proj, out,
                                     B_ * T_, C_, C_);
}

// Round 2
// 424.182 us; speedup vs baseline: 5.8497x; 5.8497x over previous
//
#include <hip/hip_runtime.h>
#include <hip/hip_bf16.h>

#define B_  4
#define T_  2048
#define C_  1024
#define H_  16
#define D_  64
#define C3_ 3072

typedef __attribute__((ext_vector_type(8))) short bf16x8;
typedef __attribute__((ext_vector_type(4))) float f32x4;
typedef unsigned short u16;

__device__ __forceinline__ u16 f2bf(float f) {
  union { float f; unsigned int u; } v; v.f = f;
  unsigned int r = (v.u + 0x7FFFu + ((v.u >> 16) & 1u)) >> 16;
  return (u16)r;
}

// ---------------------------------------------------------------------------
// fp32 -> bf16 elementwise convert (8 elems / thread)
// ---------------------------------------------------------------------------
__global__ __launch_bounds__(256)
void cvt_bf16(const float* __restrict__ in, u16* __restrict__ out, int n8) {
  int i = blockIdx.x * 256 + threadIdx.x;
  if (i >= n8) return;
  float4 a = *(const float4*)(in + (size_t)i * 8);
  float4 b = *(const float4*)(in + (size_t)i * 8 + 4);
  ushort4 lo, hi;
  lo.x = f2bf(a.x); lo.y = f2bf(a.y); lo.z = f2bf(a.z); lo.w = f2bf(a.w);
  hi.x = f2bf(b.x); hi.y = f2bf(b.y); hi.z = f2bf(b.z); hi.w = f2bf(b.w);
  *(ushort4*)(out + (size_t)i * 8) = lo;
  *(ushort4*)(out + (size_t)i * 8 + 4) = hi;
}

// ---------------------------------------------------------------------------
// transpose + convert: w[K][N] fp32 -> wT[N][K] bf16
// grid (N/64, K/16), block 256
// ---------------------------------------------------------------------------
__global__ __launch_bounds__(256)
void transcvt(const float* __restrict__ w, u16* __restrict__ wT, int K, int N) {
  int n  = blockIdx.x * 64 + (threadIdx.x & 63);
  int k0 = blockIdx.y * 16 + (threadIdx.x >> 6) * 4;
  float v0 = w[(size_t)(k0 + 0) * N + n];
  float v1 = w[(size_t)(k0 + 1) * N + n];
  float v2 = w[(size_t)(k0 + 2) * N + n];
  float v3 = w[(size_t)(k0 + 3) * N + n];
  ushort4 o; o.x = f2bf(v0); o.y = f2bf(v1); o.z = f2bf(v2); o.w = f2bf(v3);
  *(ushort4*)(wT + (size_t)n * K + k0) = o;
}

// ---------------------------------------------------------------------------
// bf16 MFMA GEMM: C[M,N] = A[M,K](bf16) @ Bt[N,K](bf16)^T + bias
// 128x128 tile, BK=32, 256 threads (4 waves, 2x2), 16x16x32 MFMA.
// LDS subtiled [sub(8)][kslot(4)][c(16)] in 16B granules -> stride-1 frag reads.
// ---------------------------------------------------------------------------
template <typename OutT>
__global__ __launch_bounds__(256)
void gemm_bf16(const u16* __restrict__ A, const u16* __restrict__ Bt,
               const float* __restrict__ bias, OutT* __restrict__ C,
               int M, int N, int K) {
  __shared__ int4 As4[512];
  __shared__ int4 Bs4[512];

  const int tid  = threadIdx.x;
  const int lane = tid & 63;
  const int wid  = tid >> 6;
  const int wr   = wid >> 1, wc = wid & 1;
  const int row0 = blockIdx.y * 128, col0 = blockIdx.x * 128;

  f32x4 acc[4][4];
#pragma unroll
  for (int m = 0; m < 4; ++m)
#pragma unroll
    for (int n = 0; n < 4; ++n) acc[m][n] = (f32x4){0.f, 0.f, 0.f, 0.f};

  // granule L -> global address. L in [0,512): sub=L>>6, q=(L>>4)&3, c=L&15
  // row = tile0 + sub*16 + c, k-slot q (8 bf16 = 16B)
  auto gA = [&](int L, int kt) {
    int sub = L >> 6, q = (L >> 4) & 3, c = L & 15;
    return (const int4*)(A + (size_t)(row0 + sub * 16 + c) * K + kt * 32 + q * 8);
  };
  auto gB = [&](int L, int kt) {
    int sub = L >> 6, q = (L >> 4) & 3, c = L & 15;
    return (const int4*)(Bt + (size_t)(col0 + sub * 16 + c) * K + kt * 32 + q * 8);
  };

  const int nk = K >> 5;
  int4 pa0 = *gA(tid, 0), pa1 = *gA(tid + 256, 0);
  int4 pb0 = *gB(tid, 0), pb1 = *gB(tid + 256, 0);

  for (int kt = 0; kt < nk; ++kt) {
    __syncthreads();               // previous tile's frag reads done
    As4[tid] = pa0; As4[tid + 256] = pa1;
    Bs4[tid] = pb0; Bs4[tid + 256] = pb1;
    __syncthreads();               // tile ready
    if (kt + 1 < nk) {             // prefetch next tile into regs (T14-lite)
      pa0 = *gA(tid, kt + 1); pa1 = *gA(tid + 256, kt + 1);
      pb0 = *gB(tid, kt + 1); pb1 = *gB(tid + 256, kt + 1);
    }
    bf16x8 a[4], b[4];
#pragma unroll
    for (int m = 0; m < 4; ++m)
      a[m] = *(const bf16x8*)(As4 + (wr * 4 + m) * 64 + lane);
#pragma unroll
    for (int n = 0; n < 4; ++n)
      b[n] = *(const bf16x8*)(Bs4 + (wc * 4 + n) * 64 + lane);
#pragma unroll
    for (int m = 0; m < 4; ++m)
#pragma unroll
      for (int n = 0; n < 4; ++n)
        acc[m][n] = __builtin_amdgcn_mfma_f32_16x16x32_bf16(a[m], b[n], acc[m][n], 0, 0, 0);
  }

  // epilogue: C/D layout col = lane&15, row = (lane>>4)*4 + r  [m89 verified]
  const int cc = lane & 15, qg = lane >> 4;
#pragma unroll
  for (int m = 0; m < 4; ++m) {
#pragma unroll
    for (int n = 0; n < 4; ++n) {
      const int gc = col0 + wc * 64 + n * 16 + cc;
      const float bv = bias[gc];
#pragma unroll
      for (int r = 0; r < 4; ++r) {
        const int gr = row0 + wr * 64 + m * 16 + qg * 4 + r;
        float val = acc[m][n][r] + bv;
        if constexpr (sizeof(OutT) == 2)
          ((u16*)C)[(size_t)gr * N + gc] = f2bf(val);
        else
          ((float*)C)[(size_t)gr * N + gc] = val;
      }
    }
  }
}

// ---------------------------------------------------------------------------
// Flash attention, bf16 MFMA. grid (T/64, H, B), block 256 (4 waves).
// Wave w owns q-rows [w*16, w*16+16) x full D=64.
// Q/K LDS: subtiled [sub(4)][ds(2)][q(4)][c(16)] 16B granules -> stride-1 reads.
// V staged transposed Vt[d][k], row stride 72 bf16 (144B).
// P routed per-wave through LDS (subtiled [ks(2)][q(4)][c(16)]).
// ---------------------------------------------------------------------------
__global__ __launch_bounds__(256)
void attn_mfma(const u16* __restrict__ qkv, u16* __restrict__ y) {
  __shared__ int4 Qs4[512];                 // 8 KB
  __shared__ int4 Ks4[512];                 // 8 KB
  __shared__ __align__(16) u16 Vt[64 * 72]; // 9 KB
  __shared__ __align__(16) u16 Ps[4 * 1024];// 8 KB (2 KB per wave)

  const int qt  = blockIdx.x;
  const int h   = blockIdx.y;
  const int b   = blockIdx.z;
  const int tid = threadIdx.x;
  const int lane = tid & 63, wq = tid >> 6;
  const int cc = lane & 15, qg = lane >> 4;
  const float scale = 0.125f;

  const u16* qbase = qkv + (size_t)(b * T_ + qt * 64) * C3_ + h * D_;
  const u16* kbase = qkv + (size_t)b * T_ * C3_ + C_ + h * D_;
  const u16* vbase = qkv + (size_t)b * T_ * C3_ + 2 * C_ + h * D_;

  // ---- stage Q (64 rows x 64 d, 512 granules) ----
#pragma unroll
  for (int p = 0; p < 2; ++p) {
    int L = p * 256 + tid;
    int sub = L >> 7, ds = (L >> 6) & 1, q = (L >> 4) & 3, c = L & 15;
    Qs4[L] = *(const int4*)(qbase + (size_t)(sub * 16 + c) * C3_ + (ds * 4 + q) * 8);
  }
  __syncthreads();

  // hoist Q fragments (per-wave, 2 d-halves)
  bf16x8 qf0 = *(const bf16x8*)(Qs4 + wq * 128 + lane);
  bf16x8 qf1 = *(const bf16x8*)(Qs4 + wq * 128 + 64 + lane);

  float m_r[4], l_r[4];
#pragma unroll
  for (int r = 0; r < 4; ++r) { m_r[r] = -1e30f; l_r[r] = 0.f; }
  f32x4 o[4];
#pragma unroll
  for (int db = 0; db < 4; ++db) o[db] = (f32x4){0.f, 0.f, 0.f, 0.f};

  u16* myP = Ps + wq * 1024;

  for (int j = 0; j <= qt; ++j) {
    __syncthreads();   // previous tile's K/Vt reads complete

    // ---- stage K tile (64 x 64) ----
#pragma unroll
    for (int p = 0; p < 2; ++p) {
      int L = p * 256 + tid;
      int sub = L >> 7, ds = (L >> 6) & 1, q = (L >> 4) & 3, c = L & 15;
      Ks4[L] = *(const int4*)(kbase + (size_t)(j * 64 + sub * 16 + c) * C3_ + (ds * 4 + q) * 8);
    }
    // ---- stage V transposed: Vt[d][k], stride 72 ----
    {
      const int d = tid & 63;
#pragma unroll
      for (int p = 0; p < 4; ++p) {
        int k0 = (tid >> 6) * 4 + p * 16;
        ushort4 vv;
        vv.x = vbase[(size_t)(j * 64 + k0 + 0) * C3_ + d];
        vv.y = vbase[(size_t)(j * 64 + k0 + 1) * C3_ + d];
        vv.z = vbase[(size_t)(j * 64 + k0 + 2) * C3_ + d];
        vv.w = vbase[(size_t)(j * 64 + k0 + 3) * C3_ + d];
        *(ushort4*)(Vt + d * 72 + k0) = vv;
      }
    }
    __syncthreads();   // K/Vt ready

    // ---- S = scale * Q K^T : 8 MFMAs ----
    f32x4 s[4];
#pragma unroll
    for (int kb = 0; kb < 4; ++kb) {
      bf16x8 kf0 = *(const bf16x8*)(Ks4 + kb * 128 + lane);
      bf16x8 kf1 = *(const bf16x8*)(Ks4 + kb * 128 + 64 + lane);
      f32x4 z = (f32x4){0.f, 0.f, 0.f, 0.f};
      z = __builtin_amdgcn_mfma_f32_16x16x32_bf16(qf0, kf0, z, 0, 0, 0);
      z = __builtin_amdgcn_mfma_f32_16x16x32_bf16(qf1, kf1, z, 0, 0, 0);
      s[kb] = z;
    }

    const bool diag = (j == qt);
#pragma unroll
    for (int kb = 0; kb < 4; ++kb)
#pragma unroll
      for (int r = 0; r < 4; ++r) {
        float v = s[kb][r] * scale;
        if (diag && (kb * 16 + cc) > (wq * 16 + qg * 4 + r)) v = -1e30f;
        s[kb][r] = v;
      }

    // ---- online softmax (rows live in 16-lane groups) ----
    float mnew[4], alpha[4];
#pragma unroll
    for (int r = 0; r < 4; ++r) {
      float mx = fmaxf(fmaxf(s[0][r], s[1][r]), fmaxf(s[2][r], s[3][r]));
      mx = fmaxf(mx, __shfl_xor(mx, 1));
      mx = fmaxf(mx, __shfl_xor(mx, 2));
      mx = fmaxf(mx, __shfl_xor(mx, 4));
      mx = fmaxf(mx, __shfl_xor(mx, 8));
      float mn = fmaxf(m_r[r], mx);
      mnew[r] = mn;
      alpha[r] = __expf(m_r[r] - mn);
      m_r[r] = mn;
    }
    float lsum[4] = {0.f, 0.f, 0.f, 0.f};
#pragma unroll
    for (int kb = 0; kb < 4; ++kb)
#pragma unroll
      for (int r = 0; r < 4; ++r) {
        float p = __expf(s[kb][r] - mnew[r]);
        s[kb][r] = p;
        lsum[r] += p;
      }
#pragma unroll
    for (int r = 0; r < 4; ++r) {
      float ls = lsum[r];
      ls += __shfl_xor(ls, 1);
      ls += __shfl_xor(ls, 2);
      ls += __shfl_xor(ls, 4);
      ls += __shfl_xor(ls, 8);
      l_r[r] = l_r[r] * alpha[r] + ls;
    }
#pragma unroll
    for (int db = 0; db < 4; ++db)
#pragma unroll
      for (int r = 0; r < 4; ++r) o[db][r] *= alpha[r];

    // ---- write P (bf16) to per-wave LDS, subtiled ----
#pragma unroll
    for (int kb = 0; kb < 4; ++kb) {
      const int col = kb * 16 + cc;
      const int ks = col >> 5, qo = (col >> 3) & 3, e = col & 7;
#pragma unroll
      for (int r = 0; r < 4; ++r)
        myP[(ks * 64 + qo * 16 + qg * 4 + r) * 8 + e] = f2bf(s[kb][r]);
    }

    // ---- O += P V : 8 MFMAs (DS in-order within wave; no barrier needed) ----
#pragma unroll
    for (int ks = 0; ks < 2; ++ks) {
      bf16x8 pf = *(const bf16x8*)((const int4*)myP + ks * 64 + lane);
#pragma unroll
      for (int db = 0; db < 4; ++db) {
        bf16x8 vf = *(const bf16x8*)((const char*)Vt + (db * 16 + cc) * 144 + ks * 64 + qg * 16);
        o[db] = __builtin_amdgcn_mfma_f32_16x16x32_bf16(pf, vf, o[db], 0, 0, 0);
      }
    }
  }

  // ---- epilogue: y = O / l  (bf16) ----
  float linv[4];
#pragma unroll
  for (int r = 0; r < 4; ++r) linv[r] = 1.0f / l_r[r];
  u16* yb = y + (size_t)(b * T_ + qt * 64 + wq * 16 + qg * 4) * C_ + h * D_ + cc;
#pragma unroll
  for (int db = 0; db < 4; ++db)
#pragma unroll
    for (int r = 0; r < 4; ++r)
      yb[(size_t)r * C_ + db * 16] = f2bf(o[db][r] * linv[r]);
}

// ---------------------------------------------------------------------------
extern "C" void kernel_launch(void* const* d_in, const int* in_sizes, int n_in,
                              void* d_out, int out_size, void* d_ws, size_t ws_size,
                              hipStream_t stream) {
  const float* x      = (const float*)d_in[0];
  const float* w_attn = (const float*)d_in[1];
  const float* b_attn = (const float*)d_in[2];
  const float* w_proj = (const float*)d_in[3];
  const float* b_proj = (const float*)d_in[4];
  float* out = (float*)d_out;

  char* ws = (char*)d_ws;
  u16* xb  = (u16*)(ws);                          // 16 MB
  u16* waT = (u16*)(ws + 16777216);               //  6 MB  [3072][1024]
  u16* wpT = (u16*)(ws + 23068672);               //  2 MB  [1024][1024]
  u16* qkv = (u16*)(ws + 25165824);               // 48 MB  [8192][3072]
  u16* yb  = (u16*)(ws + 75497472);               // 16 MB  [8192][1024]

  // convert inputs to bf16 (weights transposed to [N][K])
  cvt_bf16<<<4096, 256, 0, stream>>>(x, xb, (B_ * T_ * C_) / 8);
  transcvt<<<dim3(C3_ / 64, C_ / 16), 256, 0, stream>>>(w_attn, waT, C_, C3_);
  transcvt<<<dim3(C_ / 64, C_ / 16), 256, 0, stream>>>(w_proj, wpT, C_, C_);

  // qkv = x @ w_attn + b_attn   (bf16 out)
  gemm_bf16<u16><<<dim3(C3_ / 128, (B_ * T_) / 128), 256, 0, stream>>>(
      xb, waT, b_attn, qkv, B_ * T_, C3_, C_);

  // flash attention
  attn_mfma<<<dim3(T_ / 64, H_, B_), 256, 0, stream>>>(qkv, yb);

  // out = y @ w_proj + b_proj   (fp32 out)
  gemm_bf16<float><<<dim3(C_ / 128, (B_ * T_) / 128), 256, 0, stream>>>(
      yb, wpT, b_proj, out, B_ * T_, C_, C_);
}

// Round 3
// 354.274 us; speedup vs baseline: 7.0041x; 1.1973x over previous
//
#include <hip/hip_runtime.h>
#include <hip/hip_bf16.h>

#define B_  4
#define T_  2048
#define C_  1024
#define H_  16
#define D_  64
#define C3_ 3072

typedef __attribute__((ext_vector_type(8))) short bf16x8;
typedef __attribute__((ext_vector_type(4))) float f32x4;
typedef unsigned short u16;

__device__ __forceinline__ u16 f2bf(float f) {
  union { float f; unsigned int u; } v; v.f = f;
  unsigned int r = (v.u + 0x7FFFu + ((v.u >> 16) & 1u)) >> 16;
  return (u16)r;
}

// global -> LDS direct DMA, 16B per lane. lds ptr must be wave-uniform;
// each lane's slot = lds + lane*16 (linear). Global addr is per-lane.
__device__ __forceinline__ void gload16(void* l, const void* g) {
  __builtin_amdgcn_global_load_lds(
      (const __attribute__((address_space(1))) unsigned int*)g,
      (__attribute__((address_space(3))) unsigned int*)l, 16, 0, 0);
}

// ---------------------------------------------------------------------------
// fp32 -> bf16 elementwise convert (8 elems / thread)
// ---------------------------------------------------------------------------
__global__ __launch_bounds__(256)
void cvt_bf16(const float* __restrict__ in, u16* __restrict__ out, int n8) {
  int i = blockIdx.x * 256 + threadIdx.x;
  if (i >= n8) return;
  float4 a = *(const float4*)(in + (size_t)i * 8);
  float4 b = *(const float4*)(in + (size_t)i * 8 + 4);
  ushort4 lo, hi;
  lo.x = f2bf(a.x); lo.y = f2bf(a.y); lo.z = f2bf(a.z); lo.w = f2bf(a.w);
  hi.x = f2bf(b.x); hi.y = f2bf(b.y); hi.z = f2bf(b.z); hi.w = f2bf(b.w);
  *(ushort4*)(out + (size_t)i * 8) = lo;
  *(ushort4*)(out + (size_t)i * 8 + 4) = hi;
}

// ---------------------------------------------------------------------------
// transpose + convert: w[K][N] fp32 -> wT[N][K] bf16
// ---------------------------------------------------------------------------
__global__ __launch_bounds__(256)
void transcvt(const float* __restrict__ w, u16* __restrict__ wT, int K, int N) {
  int n  = blockIdx.x * 64 + (threadIdx.x & 63);
  int k0 = blockIdx.y * 16 + (threadIdx.x >> 6) * 4;
  float v0 = w[(size_t)(k0 + 0) * N + n];
  float v1 = w[(size_t)(k0 + 1) * N + n];
  float v2 = w[(size_t)(k0 + 2) * N + n];
  float v3 = w[(size_t)(k0 + 3) * N + n];
  ushort4 o; o.x = f2bf(v0); o.y = f2bf(v1); o.z = f2bf(v2); o.w = f2bf(v3);
  *(ushort4*)(wT + (size_t)n * K + k0) = o;
}

// ---------------------------------------------------------------------------
// bf16 MFMA GEMM (m97 structure): C[M,N] = A[M,K] @ Bt[N,K]^T + bias
// 128x128 tile, BK=32, 256 threads, global_load_lds width-16 staging.
// ---------------------------------------------------------------------------
template <typename OutT>
__global__ __launch_bounds__(256)
void gemm_bf16(const u16* __restrict__ A, const u16* __restrict__ Bt,
               const float* __restrict__ bias, OutT* __restrict__ C,
               int M, int N, int K) {
  __shared__ int4 As4[512];
  __shared__ int4 Bs4[512];

  const int tid  = threadIdx.x;
  const int lane = tid & 63;
  const int wid  = tid >> 6;
  const int wr   = wid >> 1, wc = wid & 1;
  const int row0 = blockIdx.y * 128, col0 = blockIdx.x * 128;

  f32x4 acc[4][4];
#pragma unroll
  for (int m = 0; m < 4; ++m)
#pragma unroll
    for (int n = 0; n < 4; ++n) acc[m][n] = (f32x4){0.f, 0.f, 0.f, 0.f};

  // granule L: row = base + (L>>6)*16 + (L&15), k-slot = (L>>4)&3
  const int L1 = tid, L2 = 256 + tid;
  const u16* a1 = A + (size_t)(row0 + ((L1 >> 6) * 16) + (L1 & 15)) * K + ((L1 >> 4) & 3) * 8;
  const u16* a2 = A + (size_t)(row0 + ((L2 >> 6) * 16) + (L2 & 15)) * K + ((L2 >> 4) & 3) * 8;
  const u16* b1 = Bt + (size_t)(col0 + ((L1 >> 6) * 16) + (L1 & 15)) * K + ((L1 >> 4) & 3) * 8;
  const u16* b2 = Bt + (size_t)(col0 + ((L2 >> 6) * 16) + (L2 & 15)) * K + ((L2 >> 4) & 3) * 8;

  const int nk = K >> 5;
  for (int kt = 0; kt < nk; ++kt) {
    __syncthreads();               // prev tile's frag reads done
    gload16(As4 + wid * 64, a1);
    gload16(As4 + 256 + wid * 64, a2);
    gload16(Bs4 + wid * 64, b1);
    gload16(Bs4 + 256 + wid * 64, b2);
    a1 += 32; a2 += 32; b1 += 32; b2 += 32;
    __syncthreads();               // vmcnt(0) drain: tile ready

    bf16x8 a[4], b[4];
#pragma unroll
    for (int m = 0; m < 4; ++m)
      a[m] = *(const bf16x8*)(As4 + (wr * 4 + m) * 64 + lane);
#pragma unroll
    for (int n = 0; n < 4; ++n)
      b[n] = *(const bf16x8*)(Bs4 + (wc * 4 + n) * 64 + lane);
#pragma unroll
    for (int m = 0; m < 4; ++m)
#pragma unroll
      for (int n = 0; n < 4; ++n)
        acc[m][n] = __builtin_amdgcn_mfma_f32_16x16x32_bf16(a[m], b[n], acc[m][n], 0, 0, 0);
  }

  const int cc = lane & 15, qg = lane >> 4;
#pragma unroll
  for (int m = 0; m < 4; ++m) {
#pragma unroll
    for (int n = 0; n < 4; ++n) {
      const int gc = col0 + wc * 64 + n * 16 + cc;
      const float bv = bias[gc];
#pragma unroll
      for (int r = 0; r < 4; ++r) {
        const int gr = row0 + wr * 64 + m * 16 + qg * 4 + r;
        float val = acc[m][n][r] + bv;
        if constexpr (sizeof(OutT) == 2)
          ((u16*)C)[(size_t)gr * N + gc] = f2bf(val);
        else
          ((float*)C)[(size_t)gr * N + gc] = val;
      }
    }
  }
}

// ---------------------------------------------------------------------------
// Flash attention v3: 8 waves (512 thr), 128 q-rows/block, KV tile 64.
// Q in regs; K,V^T granule-linear LDS, reg-prefetched (async-STAGE split);
// per-wave P granule buffer; heavy-blocks-first for causal balance.
// ---------------------------------------------------------------------------
__global__ __launch_bounds__(512, 4)
void attn_mfma(const u16* __restrict__ qkv, u16* __restrict__ yout) {
  __shared__ int4 Ks4[512];        // 8 KB  K granules
  __shared__ int4 Vs4[512];        // 8 KB  V^T granules
  __shared__ int4 Ps4[8 * 128];    // 16 KB per-wave P granules

  const int qb  = (int)gridDim.x - 1 - (int)blockIdx.x;  // heavy-first
  const int h   = blockIdx.y;
  const int b   = blockIdx.z;
  const int tid = threadIdx.x;
  const int lane = tid & 63, wq = tid >> 6;
  const int cc = lane & 15, qg = lane >> 4;
  const float scale = 0.125f;

  const u16* qbase = qkv + (size_t)(b * T_ + qb * 128) * C3_ + h * D_;
  const u16* kbase = qkv + (size_t)b * T_ * C3_ + C_ + h * D_;
  const u16* vbase = qkv + (size_t)b * T_ * C3_ + 2 * C_ + h * D_;

  // Q fragments direct to regs: wave wq owns rows [wq*16, wq*16+16)
  bf16x8 qf0 = *(const bf16x8*)(qbase + (size_t)(wq * 16 + cc) * C3_ + qg * 8);
  bf16x8 qf1 = *(const bf16x8*)(qbase + (size_t)(wq * 16 + cc) * C3_ + 32 + qg * 8);

  // staging geometry for this thread (granule = tid)
  const u16* kg = kbase + (size_t)((tid >> 7) * 16 + (tid & 15)) * C3_ +
                  ((tid >> 6) & 1) * 32 + ((tid >> 4) & 3) * 8;
  const u16* vg = vbase + (size_t)(((tid >> 6) & 1) * 32 + ((tid >> 4) & 3) * 8) * C3_ +
                  (tid >> 7) * 16 + (tid & 15);

  const int jmax = 2 * qb + 1;
  const int qrow0w = qb * 128 + wq * 16;   // wave's first absolute q-row

  // prologue: prefetch tile 0 into regs
  int4 kpref = *(const int4*)kg;
  u16 vp[8];
#pragma unroll
  for (int e = 0; e < 8; ++e) vp[e] = vg[(size_t)e * C3_];

  float m_r[4], l_r[4];
#pragma unroll
  for (int r = 0; r < 4; ++r) { m_r[r] = -1e30f; l_r[r] = 0.f; }
  f32x4 o[4];
#pragma unroll
  for (int db = 0; db < 4; ++db) o[db] = (f32x4){0.f, 0.f, 0.f, 0.f};

  for (int j = 0; j <= jmax; ++j) {
    __syncthreads();   // all waves done reading previous tile's LDS
    Ks4[tid] = kpref;
    {
      int4 vv; u16* vvp = (u16*)&vv;
#pragma unroll
      for (int e = 0; e < 8; ++e) vvp[e] = vp[e];
      Vs4[tid] = vv;
    }
    __syncthreads();   // K/V^T tile ready

    if (j < jmax) {    // prefetch next tile (latency hides under compute)
      const u16* kg2 = kg + (size_t)(j + 1) * 64 * C3_;
      kpref = *(const int4*)kg2;
      const u16* vg2 = vg + (size_t)(j + 1) * 64 * C3_;
#pragma unroll
      for (int e = 0; e < 8; ++e) vp[e] = vg2[(size_t)e * C3_];
    }

    if (j * 64 > qrow0w + 15) continue;   // wave fully masked from here on

    // ---- S = scale * Q K^T : 8 MFMAs ----
    f32x4 s[4];
#pragma unroll
    for (int kb = 0; kb < 4; ++kb) {
      bf16x8 kf0 = *(const bf16x8*)(Ks4 + kb * 128 + lane);
      bf16x8 kf1 = *(const bf16x8*)(Ks4 + kb * 128 + 64 + lane);
      f32x4 z = (f32x4){0.f, 0.f, 0.f, 0.f};
      z = __builtin_amdgcn_mfma_f32_16x16x32_bf16(qf0, kf0, z, 0, 0, 0);
      z = __builtin_amdgcn_mfma_f32_16x16x32_bf16(qf1, kf1, z, 0, 0, 0);
      s[kb] = z;
    }

    const bool needmask = (j * 64 + 63) > qrow0w;
#pragma unroll
    for (int kb = 0; kb < 4; ++kb)
#pragma unroll
      for (int r = 0; r < 4; ++r) {
        float v = s[kb][r] * scale;
        if (needmask && (j * 64 + kb * 16 + cc) > (qrow0w + qg * 4 + r)) v = -1e30f;
        s[kb][r] = v;
      }

    // ---- online softmax (rows live in 16-lane groups) ----
    float mnew[4], alpha[4];
#pragma unroll
    for (int r = 0; r < 4; ++r) {
      float mx = fmaxf(fmaxf(s[0][r], s[1][r]), fmaxf(s[2][r], s[3][r]));
      mx = fmaxf(mx, __shfl_xor(mx, 1));
      mx = fmaxf(mx, __shfl_xor(mx, 2));
      mx = fmaxf(mx, __shfl_xor(mx, 4));
      mx = fmaxf(mx, __shfl_xor(mx, 8));
      float mn = fmaxf(m_r[r], mx);
      mnew[r] = mn;
      alpha[r] = __expf(m_r[r] - mn);
      m_r[r] = mn;
    }
    float lsum[4] = {0.f, 0.f, 0.f, 0.f};
#pragma unroll
    for (int kb = 0; kb < 4; ++kb)
#pragma unroll
      for (int r = 0; r < 4; ++r) {
        float p = __expf(s[kb][r] - mnew[r]);
        s[kb][r] = p;
        lsum[r] += p;
      }
#pragma unroll
    for (int r = 0; r < 4; ++r) {
      float ls = lsum[r];
      ls += __shfl_xor(ls, 1);
      ls += __shfl_xor(ls, 2);
      ls += __shfl_xor(ls, 4);
      ls += __shfl_xor(ls, 8);
      l_r[r] = l_r[r] * alpha[r] + ls;
    }
#pragma unroll
    for (int db = 0; db < 4; ++db)
#pragma unroll
      for (int r = 0; r < 4; ++r) o[db][r] *= alpha[r];

    // ---- write P (bf16) to per-wave LDS granules ----
    u16* myP = (u16*)(Ps4 + wq * 128);
#pragma unroll
    for (int kb = 0; kb < 4; ++kb) {
      const int col = kb * 16 + cc;
      const int ks = col >> 5, qo = (col >> 3) & 3, e = col & 7;
#pragma unroll
      for (int r = 0; r < 4; ++r)
        myP[(ks * 64 + qo * 16 + qg * 4 + r) * 8 + e] = f2bf(s[kb][r]);
    }

    // ---- O += P V : 8 MFMAs (same-wave DS ordering, no barrier) ----
#pragma unroll
    for (int ks = 0; ks < 2; ++ks) {
      bf16x8 pf = *(const bf16x8*)(Ps4 + wq * 128 + ks * 64 + lane);
#pragma unroll
      for (int db = 0; db < 4; ++db) {
        bf16x8 vf = *(const bf16x8*)(Vs4 + db * 128 + ks * 64 + lane);
        o[db] = __builtin_amdgcn_mfma_f32_16x16x32_bf16(pf, vf, o[db], 0, 0, 0);
      }
    }
  }

  // ---- epilogue: y = O / l ----
  float linv[4];
#pragma unroll
  for (int r = 0; r < 4; ++r) linv[r] = 1.0f / l_r[r];
  u16* yb = yout + (size_t)(b * T_ + qb * 128 + wq * 16 + qg * 4) * C_ + h * D_ + cc;
#pragma unroll
  for (int db = 0; db < 4; ++db)
#pragma unroll
    for (int r = 0; r < 4; ++r)
      yb[(size_t)r * C_ + db * 16] = f2bf(o[db][r] * linv[r]);
}

// ---------------------------------------------------------------------------
extern "C" void kernel_launch(void* const* d_in, const int* in_sizes, int n_in,
                              void* d_out, int out_size, void* d_ws, size_t ws_size,
                              hipStream_t stream) {
  const float* x      = (const float*)d_in[0];
  const float* w_attn = (const float*)d_in[1];
  const float* b_attn = (const float*)d_in[2];
  const float* w_proj = (const float*)d_in[3];
  const float* b_proj = (const float*)d_in[4];
  float* out = (float*)d_out;

  char* ws = (char*)d_ws;
  u16* xb  = (u16*)(ws);                          // 16 MB
  u16* waT = (u16*)(ws + 16777216);               //  6 MB  [3072][1024]
  u16* wpT = (u16*)(ws + 23068672);               //  2 MB  [1024][1024]
  u16* qkv = (u16*)(ws + 25165824);               // 48 MB  [8192][3072]
  u16* yb  = (u16*)(ws + 75497472);               // 16 MB  [8192][1024]

  cvt_bf16<<<4096, 256, 0, stream>>>(x, xb, (B_ * T_ * C_) / 8);
  transcvt<<<dim3(C3_ / 64, C_ / 16), 256, 0, stream>>>(w_attn, waT, C_, C3_);
  transcvt<<<dim3(C_ / 64, C_ / 16), 256, 0, stream>>>(w_proj, wpT, C_, C_);

  gemm_bf16<u16><<<dim3(C3_ / 128, (B_ * T_) / 128), 256, 0, stream>>>(
      xb, waT, b_attn, qkv, B_ * T_, C3_, C_);

  attn_mfma<<<dim3(T_ / 128, H_, B_), 512, 0, stream>>>(qkv, yb);

  gemm_bf16<float><<<dim3(C_ / 128, (B_ * T_) / 128), 256, 0, stream>>>(
      yb, wpT, b_proj, out, B_ * T_, C_, C_);
}

// Round 4
// 307.546 us; speedup vs baseline: 8.0682x; 1.1519x over previous
//
#include <hip/hip_runtime.h>
#include <hip/hip_bf16.h>

#define B_  4
#define T_  2048
#define C_  1024
#define H_  16
#define D_  64
#define C3_ 3072

typedef __attribute__((ext_vector_type(8))) short bf16x8;
typedef __attribute__((ext_vector_type(4))) float f32x4;
typedef unsigned short u16;

__device__ __forceinline__ u16 f2bf(float f) {
  union { float f; unsigned int u; } v; v.f = f;
  unsigned int r = (v.u + 0x7FFFu + ((v.u >> 16) & 1u)) >> 16;
  return (u16)r;
}

__device__ __forceinline__ void gload16(void* l, const void* g) {
  __builtin_amdgcn_global_load_lds(
      (const __attribute__((address_space(1))) unsigned int*)g,
      (__attribute__((address_space(3))) unsigned int*)l, 16, 0, 0);
}

// ---------------------------------------------------------------------------
__global__ __launch_bounds__(256)
void cvt_bf16(const float* __restrict__ in, u16* __restrict__ out, int n8) {
  int i = blockIdx.x * 256 + threadIdx.x;
  if (i >= n8) return;
  float4 a = *(const float4*)(in + (size_t)i * 8);
  float4 b = *(const float4*)(in + (size_t)i * 8 + 4);
  ushort4 lo, hi;
  lo.x = f2bf(a.x); lo.y = f2bf(a.y); lo.z = f2bf(a.z); lo.w = f2bf(a.w);
  hi.x = f2bf(b.x); hi.y = f2bf(b.y); hi.z = f2bf(b.z); hi.w = f2bf(b.w);
  *(ushort4*)(out + (size_t)i * 8) = lo;
  *(ushort4*)(out + (size_t)i * 8 + 4) = hi;
}

__global__ __launch_bounds__(256)
void transcvt(const float* __restrict__ w, u16* __restrict__ wT, int K, int N) {
  int n  = blockIdx.x * 64 + (threadIdx.x & 63);
  int k0 = blockIdx.y * 16 + (threadIdx.x >> 6) * 4;
  float v0 = w[(size_t)(k0 + 0) * N + n];
  float v1 = w[(size_t)(k0 + 1) * N + n];
  float v2 = w[(size_t)(k0 + 2) * N + n];
  float v3 = w[(size_t)(k0 + 3) * N + n];
  ushort4 o; o.x = f2bf(v0); o.y = f2bf(v1); o.z = f2bf(v2); o.w = f2bf(v3);
  *(ushort4*)(wT + (size_t)n * K + k0) = o;
}

// ---------------------------------------------------------------------------
// bf16 MFMA GEMM (m97 structure), unchanged from R3.
// ---------------------------------------------------------------------------
template <typename OutT>
__global__ __launch_bounds__(256)
void gemm_bf16(const u16* __restrict__ A, const u16* __restrict__ Bt,
               const float* __restrict__ bias, OutT* __restrict__ C,
               int M, int N, int K) {
  __shared__ int4 As4[512];
  __shared__ int4 Bs4[512];

  const int tid  = threadIdx.x;
  const int lane = tid & 63;
  const int wid  = tid >> 6;
  const int wr   = wid >> 1, wc = wid & 1;
  const int row0 = blockIdx.y * 128, col0 = blockIdx.x * 128;

  f32x4 acc[4][4];
#pragma unroll
  for (int m = 0; m < 4; ++m)
#pragma unroll
    for (int n = 0; n < 4; ++n) acc[m][n] = (f32x4){0.f, 0.f, 0.f, 0.f};

  const int L1 = tid, L2 = 256 + tid;
  const u16* a1 = A + (size_t)(row0 + ((L1 >> 6) * 16) + (L1 & 15)) * K + ((L1 >> 4) & 3) * 8;
  const u16* a2 = A + (size_t)(row0 + ((L2 >> 6) * 16) + (L2 & 15)) * K + ((L2 >> 4) & 3) * 8;
  const u16* b1 = Bt + (size_t)(col0 + ((L1 >> 6) * 16) + (L1 & 15)) * K + ((L1 >> 4) & 3) * 8;
  const u16* b2 = Bt + (size_t)(col0 + ((L2 >> 6) * 16) + (L2 & 15)) * K + ((L2 >> 4) & 3) * 8;

  const int nk = K >> 5;
  for (int kt = 0; kt < nk; ++kt) {
    __syncthreads();
    gload16(As4 + wid * 64, a1);
    gload16(As4 + 256 + wid * 64, a2);
    gload16(Bs4 + wid * 64, b1);
    gload16(Bs4 + 256 + wid * 64, b2);
    a1 += 32; a2 += 32; b1 += 32; b2 += 32;
    __syncthreads();

    bf16x8 a[4], b[4];
#pragma unroll
    for (int m = 0; m < 4; ++m)
      a[m] = *(const bf16x8*)(As4 + (wr * 4 + m) * 64 + lane);
#pragma unroll
    for (int n = 0; n < 4; ++n)
      b[n] = *(const bf16x8*)(Bs4 + (wc * 4 + n) * 64 + lane);
#pragma unroll
    for (int m = 0; m < 4; ++m)
#pragma unroll
      for (int n = 0; n < 4; ++n)
        acc[m][n] = __builtin_amdgcn_mfma_f32_16x16x32_bf16(a[m], b[n], acc[m][n], 0, 0, 0);
  }

  const int cc = lane & 15, qg = lane >> 4;
#pragma unroll
  for (int m = 0; m < 4; ++m) {
#pragma unroll
    for (int n = 0; n < 4; ++n) {
      const int gc = col0 + wc * 64 + n * 16 + cc;
      const float bv = bias[gc];
#pragma unroll
      for (int r = 0; r < 4; ++r) {
        const int gr = row0 + wr * 64 + m * 16 + qg * 4 + r;
        float val = acc[m][n][r] + bv;
        if constexpr (sizeof(OutT) == 2)
          ((u16*)C)[(size_t)gr * N + gc] = f2bf(val);
        else
          ((float*)C)[(size_t)gr * N + gc] = val;
      }
    }
  }
}

// ---------------------------------------------------------------------------
// Flash attention v4: causal-paired blocks for uniform duration.
// Block = 512 thr (8 waves). Waves 0-3: q-tile i (64 rows); waves 4-7:
// q-tile 31-i. KV loop j=0..31-i staged once for both. XCD-bh grouping.
// Softmax in exp2 domain; defer-rescale; setprio around MFMA.
// ---------------------------------------------------------------------------
#define CSCALE 0.1803368801111204f   /* (1/8) * log2(e) */

__global__ __launch_bounds__(512, 4)
void attn_mfma(const u16* __restrict__ qkv, u16* __restrict__ yout) {
  __shared__ int4 Ks4[512];        // 8 KB  K granules
  __shared__ int4 Vs4[512];        // 8 KB  V^T granules
  __shared__ int4 Ps4[8 * 128];    // 16 KB per-wave P granules

  // XCD-bh decode: dispatch n -> XCD n%8 (round-robin). Keep one (b,h)'s
  // 16 pair-blocks on one XCD for K/V L2 reuse.
  const int n   = blockIdx.x;
  const int xcd = n & 7, t = n >> 3;
  const int bh  = xcd * 8 + (t >> 4);
  const int i   = t & 15;                 // pair index; staging span 32-i
  const int b   = bh >> 4, h = bh & 15;

  const int tid = threadIdx.x;
  const int lane = tid & 63, wq = tid >> 6;
  const int sub = wq & 3;
  const int cc = lane & 15, qg = lane >> 4;

  const int qtile  = (wq < 4) ? i : (31 - i);   // this wave's 64-row q-tile
  const int qrow0w = qtile * 64 + sub * 16;     // wave's first q-row
  const int jn     = 32 - i;                    // kv tiles staged

  const u16* kbase = qkv + (size_t)b * T_ * C3_ + C_ + h * D_;
  const u16* vbase = qkv + (size_t)b * T_ * C3_ + 2 * C_ + h * D_;
  const u16* qbase = qkv + (size_t)(b * T_ + qrow0w) * C3_ + h * D_;

  bf16x8 qf0 = *(const bf16x8*)(qbase + (size_t)cc * C3_ + qg * 8);
  bf16x8 qf1 = *(const bf16x8*)(qbase + (size_t)cc * C3_ + 32 + qg * 8);

  // staging geometry (granule = tid)
  const u16* kg = kbase + (size_t)((tid >> 7) * 16 + (tid & 15)) * C3_ +
                  ((tid >> 6) & 1) * 32 + ((tid >> 4) & 3) * 8;
  const u16* vg = vbase + (size_t)(((tid >> 6) & 1) * 32 + ((tid >> 4) & 3) * 8) * C3_ +
                  (tid >> 7) * 16 + (tid & 15);

  int4 kpref = *(const int4*)kg;
  u16 vp[8];
#pragma unroll
  for (int e = 0; e < 8; ++e) vp[e] = vg[(size_t)e * C3_];

  float m_r[4], l_r[4];
#pragma unroll
  for (int r = 0; r < 4; ++r) { m_r[r] = -1e30f; l_r[r] = 0.f; }
  f32x4 o[4];
#pragma unroll
  for (int db = 0; db < 4; ++db) o[db] = (f32x4){0.f, 0.f, 0.f, 0.f};

  for (int j = 0; j < jn; ++j) {
    __syncthreads();                      // all waves done reading prev LDS
    Ks4[tid] = kpref;
    {
      int4 vv; u16* vvp = (u16*)&vv;
#pragma unroll
      for (int e = 0; e < 8; ++e) vvp[e] = vp[e];
      Vs4[tid] = vv;
    }
    __syncthreads();                      // tile ready

    if (j + 1 < jn) {                     // prefetch next tile into regs
      const u16* kg2 = kg + (size_t)(j + 1) * 64 * C3_;
      kpref = *(const int4*)kg2;
      const u16* vg2 = vg + (size_t)(j + 1) * 64 * C3_;
#pragma unroll
      for (int e = 0; e < 8; ++e) vp[e] = vg2[(size_t)e * C3_];
    }

    if (j > qtile) continue;              // wave past its causal range

    // ---- S = Q K^T : 8 MFMAs ----
    __builtin_amdgcn_s_setprio(1);
    f32x4 s[4];
#pragma unroll
    for (int kb = 0; kb < 4; ++kb) {
      bf16x8 kf0 = *(const bf16x8*)(Ks4 + kb * 128 + lane);
      bf16x8 kf1 = *(const bf16x8*)(Ks4 + kb * 128 + 64 + lane);
      f32x4 z = (f32x4){0.f, 0.f, 0.f, 0.f};
      z = __builtin_amdgcn_mfma_f32_16x16x32_bf16(qf0, kf0, z, 0, 0, 0);
      z = __builtin_amdgcn_mfma_f32_16x16x32_bf16(qf1, kf1, z, 0, 0, 0);
      s[kb] = z;
    }
    __builtin_amdgcn_s_setprio(0);

    // exp2 domain: t = s * scale * log2e
#pragma unroll
    for (int kb = 0; kb < 4; ++kb)
#pragma unroll
      for (int r = 0; r < 4; ++r) s[kb][r] *= CSCALE;

    if (j == qtile) {                     // wave-uniform diagonal mask
#pragma unroll
      for (int kb = 0; kb < 4; ++kb)
#pragma unroll
        for (int r = 0; r < 4; ++r)
          if ((j * 64 + kb * 16 + cc) > (qrow0w + qg * 4 + r)) s[kb][r] = -1e30f;
    }

    // row max (rows live in 16-lane groups)
    float mx[4];
#pragma unroll
    for (int r = 0; r < 4; ++r) {
      float m0 = fmaxf(fmaxf(s[0][r], s[1][r]), fmaxf(s[2][r], s[3][r]));
      m0 = fmaxf(m0, __shfl_xor(m0, 1));
      m0 = fmaxf(m0, __shfl_xor(m0, 2));
      m0 = fmaxf(m0, __shfl_xor(m0, 4));
      m0 = fmaxf(m0, __shfl_xor(m0, 8));
      mx[r] = m0;
    }
    // defer-rescale: skip alpha path when no row max grew (alpha==1 exact)
    float g = fmaxf(fmaxf(mx[0] - m_r[0], mx[1] - m_r[1]),
                    fmaxf(mx[2] - m_r[2], mx[3] - m_r[3]));
    if (!__all(g <= 0.0f)) {
#pragma unroll
      for (int r = 0; r < 4; ++r) {
        float mn = fmaxf(m_r[r], mx[r]);
        float al = exp2f(m_r[r] - mn);
        m_r[r] = mn;
        l_r[r] *= al;
#pragma unroll
        for (int db = 0; db < 4; ++db) o[db][r] *= al;
      }
    }

    float lsum[4] = {0.f, 0.f, 0.f, 0.f};
#pragma unroll
    for (int kb = 0; kb < 4; ++kb)
#pragma unroll
      for (int r = 0; r < 4; ++r) {
        float p = exp2f(s[kb][r] - m_r[r]);
        s[kb][r] = p;
        lsum[r] += p;
      }
#pragma unroll
    for (int r = 0; r < 4; ++r) {
      float ls = lsum[r];
      ls += __shfl_xor(ls, 1);
      ls += __shfl_xor(ls, 2);
      ls += __shfl_xor(ls, 4);
      ls += __shfl_xor(ls, 8);
      l_r[r] += ls;
    }

    // ---- write P (bf16) to per-wave LDS granules ----
    u16* myP = (u16*)(Ps4 + wq * 128);
#pragma unroll
    for (int kb = 0; kb < 4; ++kb) {
      const int col = kb * 16 + cc;
      const int ks = col >> 5, qo = (col >> 3) & 3, e = col & 7;
#pragma unroll
      for (int r = 0; r < 4; ++r)
        myP[(ks * 64 + qo * 16 + qg * 4 + r) * 8 + e] = f2bf(s[kb][r]);
    }

    // ---- O += P V : 8 MFMAs ----
    __builtin_amdgcn_s_setprio(1);
#pragma unroll
    for (int ks = 0; ks < 2; ++ks) {
      bf16x8 pf = *(const bf16x8*)(Ps4 + wq * 128 + ks * 64 + lane);
#pragma unroll
      for (int db = 0; db < 4; ++db) {
        bf16x8 vf = *(const bf16x8*)(Vs4 + db * 128 + ks * 64 + lane);
        o[db] = __builtin_amdgcn_mfma_f32_16x16x32_bf16(pf, vf, o[db], 0, 0, 0);
      }
    }
    __builtin_amdgcn_s_setprio(0);
  }

  // ---- epilogue: y = O / l ----
  float linv[4];
#pragma unroll
  for (int r = 0; r < 4; ++r) linv[r] = 1.0f / l_r[r];
  u16* yb = yout + (size_t)(b * T_ + qrow0w + qg * 4) * C_ + h * D_ + cc;
#pragma unroll
  for (int db = 0; db < 4; ++db)
#pragma unroll
    for (int r = 0; r < 4; ++r)
      yb[(size_t)r * C_ + db * 16] = f2bf(o[db][r] * linv[r]);
}

// ---------------------------------------------------------------------------
extern "C" void kernel_launch(void* const* d_in, const int* in_sizes, int n_in,
                              void* d_out, int out_size, void* d_ws, size_t ws_size,
                              hipStream_t stream) {
  const float* x      = (const float*)d_in[0];
  const float* w_attn = (const float*)d_in[1];
  const float* b_attn = (const float*)d_in[2];
  const float* w_proj = (const float*)d_in[3];
  const float* b_proj = (const float*)d_in[4];
  float* out = (float*)d_out;

  char* ws = (char*)d_ws;
  u16* xb  = (u16*)(ws);                          // 16 MB
  u16* waT = (u16*)(ws + 16777216);               //  6 MB  [3072][1024]
  u16* wpT = (u16*)(ws + 23068672);               //  2 MB  [1024][1024]
  u16* qkv = (u16*)(ws + 25165824);               // 48 MB  [8192][3072]
  u16* yb  = (u16*)(ws + 75497472);               // 16 MB  [8192][1024]

  cvt_bf16<<<4096, 256, 0, stream>>>(x, xb, (B_ * T_ * C_) / 8);
  transcvt<<<dim3(C3_ / 64, C_ / 16), 256, 0, stream>>>(w_attn, waT, C_, C3_);
  transcvt<<<dim3(C_ / 64, C_ / 16), 256, 0, stream>>>(w_proj, wpT, C_, C_);

  gemm_bf16<u16><<<dim3(C3_ / 128, (B_ * T_) / 128), 256, 0, stream>>>(
      xb, waT, b_attn, qkv, B_ * T_, C3_, C_);

  attn_mfma<<<dim3(16 * H_ * B_), 512, 0, stream>>>(qkv, yb);

  gemm_bf16<float><<<dim3(C_ / 128, (B_ * T_) / 128), 256, 0, stream>>>(
      yb, wpT, b_proj, out, B_ * T_, C_, C_);
}

// Round 5
// 259.691 us; speedup vs baseline: 9.5551x; 1.1843x over previous
//
#include <hip/hip_runtime.h>
#include <hip/hip_bf16.h>

#define B_  4
#define T_  2048
#define C_  1024
#define H_  16
#define D_  64
#define C3_ 3072

typedef __attribute__((ext_vector_type(8))) short bf16x8;
typedef __attribute__((ext_vector_type(4))) float f32x4;
typedef unsigned short u16;

#define CSCALE 0.1803368801111204f   /* (1/8) * log2(e) */

__device__ __forceinline__ u16 f2bf(float f) {
  union { float f; unsigned int u; } v; v.f = f;
  unsigned int r = (v.u + 0x7FFFu + ((v.u >> 16) & 1u)) >> 16;
  return (u16)r;
}

__device__ __forceinline__ void gload16(void* l, const void* g) {
  __builtin_amdgcn_global_load_lds(
      (const __attribute__((address_space(1))) unsigned int*)g,
      (__attribute__((address_space(3))) unsigned int*)l, 16, 0, 0);
}

// ---------------------------------------------------------------------------
__global__ __launch_bounds__(256)
void cvt_bf16(const float* __restrict__ in, u16* __restrict__ out, int n8) {
  int i = blockIdx.x * 256 + threadIdx.x;
  if (i >= n8) return;
  float4 a = *(const float4*)(in + (size_t)i * 8);
  float4 b = *(const float4*)(in + (size_t)i * 8 + 4);
  ushort4 lo, hi;
  lo.x = f2bf(a.x); lo.y = f2bf(a.y); lo.z = f2bf(a.z); lo.w = f2bf(a.w);
  hi.x = f2bf(b.x); hi.y = f2bf(b.y); hi.z = f2bf(b.z); hi.w = f2bf(b.w);
  *(ushort4*)(out + (size_t)i * 8) = lo;
  *(ushort4*)(out + (size_t)i * 8 + 4) = hi;
}

__global__ __launch_bounds__(256)
void transcvt(const float* __restrict__ w, u16* __restrict__ wT, int K, int N) {
  int n  = blockIdx.x * 64 + (threadIdx.x & 63);
  int k0 = blockIdx.y * 16 + (threadIdx.x >> 6) * 4;
  float v0 = w[(size_t)(k0 + 0) * N + n];
  float v1 = w[(size_t)(k0 + 1) * N + n];
  float v2 = w[(size_t)(k0 + 2) * N + n];
  float v3 = w[(size_t)(k0 + 3) * N + n];
  ushort4 o; o.x = f2bf(v0); o.y = f2bf(v1); o.z = f2bf(v2); o.w = f2bf(v3);
  *(ushort4*)(wT + (size_t)n * K + k0) = o;
}

// ---------------------------------------------------------------------------
// bf16 MFMA GEMM. qscale_cols: columns < qscale_cols get *CSCALE (folds the
// attention scale & log2e into the q part of the qkv projection).
// ---------------------------------------------------------------------------
template <typename OutT>
__global__ __launch_bounds__(256)
void gemm_bf16(const u16* __restrict__ A, const u16* __restrict__ Bt,
               const float* __restrict__ bias, OutT* __restrict__ C,
               int M, int N, int K, int qscale_cols) {
  __shared__ int4 As4[512];
  __shared__ int4 Bs4[512];

  const int tid  = threadIdx.x;
  const int lane = tid & 63;
  const int wid  = tid >> 6;
  const int wr   = wid >> 1, wc = wid & 1;
  const int row0 = blockIdx.y * 128, col0 = blockIdx.x * 128;

  f32x4 acc[4][4];
#pragma unroll
  for (int m = 0; m < 4; ++m)
#pragma unroll
    for (int n = 0; n < 4; ++n) acc[m][n] = (f32x4){0.f, 0.f, 0.f, 0.f};

  const int L1 = tid, L2 = 256 + tid;
  const u16* a1 = A + (size_t)(row0 + ((L1 >> 6) * 16) + (L1 & 15)) * K + ((L1 >> 4) & 3) * 8;
  const u16* a2 = A + (size_t)(row0 + ((L2 >> 6) * 16) + (L2 & 15)) * K + ((L2 >> 4) & 3) * 8;
  const u16* b1 = Bt + (size_t)(col0 + ((L1 >> 6) * 16) + (L1 & 15)) * K + ((L1 >> 4) & 3) * 8;
  const u16* b2 = Bt + (size_t)(col0 + ((L2 >> 6) * 16) + (L2 & 15)) * K + ((L2 >> 4) & 3) * 8;

  const int nk = K >> 5;
  for (int kt = 0; kt < nk; ++kt) {
    __syncthreads();
    gload16(As4 + wid * 64, a1);
    gload16(As4 + 256 + wid * 64, a2);
    gload16(Bs4 + wid * 64, b1);
    gload16(Bs4 + 256 + wid * 64, b2);
    a1 += 32; a2 += 32; b1 += 32; b2 += 32;
    __syncthreads();

    bf16x8 a[4], b[4];
#pragma unroll
    for (int m = 0; m < 4; ++m)
      a[m] = *(const bf16x8*)(As4 + (wr * 4 + m) * 64 + lane);
#pragma unroll
    for (int n = 0; n < 4; ++n)
      b[n] = *(const bf16x8*)(Bs4 + (wc * 4 + n) * 64 + lane);
#pragma unroll
    for (int m = 0; m < 4; ++m)
#pragma unroll
      for (int n = 0; n < 4; ++n)
        acc[m][n] = __builtin_amdgcn_mfma_f32_16x16x32_bf16(a[m], b[n], acc[m][n], 0, 0, 0);
  }

  const int cc = lane & 15, qg = lane >> 4;
#pragma unroll
  for (int m = 0; m < 4; ++m) {
#pragma unroll
    for (int n = 0; n < 4; ++n) {
      const int gc = col0 + wc * 64 + n * 16 + cc;
      const float bv = bias[gc];
      const float sc = (gc < qscale_cols) ? CSCALE : 1.0f;
#pragma unroll
      for (int r = 0; r < 4; ++r) {
        const int gr = row0 + wr * 64 + m * 16 + qg * 4 + r;
        float val = (acc[m][n][r] + bv) * sc;
        if constexpr (sizeof(OutT) == 2)
          ((u16*)C)[(size_t)gr * N + gc] = f2bf(val);
        else
          ((float*)C)[(size_t)gr * N + gc] = val;
      }
    }
  }
}

// ---------------------------------------------------------------------------
// Flash attention v5: swapped QK^T (S^T = K Q^T) so each lane owns one q-row
// (q = lane&15) with 16 kv values in registers -> in-lane softmax, packed
// cvt_pk P conversion, ds_write_b64, deferred l-reduction.
// Causal-paired blocks (i, 31-i), XCD-bh grouping as R4.
// ---------------------------------------------------------------------------
__global__ __launch_bounds__(512, 4)
void attn_mfma(const u16* __restrict__ qkv, u16* __restrict__ yout) {
  __shared__ int4 Ks4[512];        // 8 KB  K granules
  __shared__ int4 Vs4[512];        // 8 KB  V^T granules
  __shared__ int4 Ps4[8 * 128];    // 16 KB per-wave P granules

  const int n   = blockIdx.x;
  const int xcd = n & 7, t = n >> 3;
  const int bh  = xcd * 8 + (t >> 4);
  const int i   = t & 15;
  const int b   = bh >> 4, h = bh & 15;

  const int tid = threadIdx.x;
  const int lane = tid & 63, wq = tid >> 6;
  const int sub = wq & 3;
  const int cc = lane & 15, qg = lane >> 4;

  const int qtile  = (wq < 4) ? i : (31 - i);
  const int qrow0w = qtile * 64 + sub * 16;
  const int jn     = 32 - i;
  const int qabs   = qrow0w + cc;          // this lane's q row

  const u16* kbase = qkv + (size_t)b * T_ * C3_ + C_ + h * D_;
  const u16* vbase = qkv + (size_t)b * T_ * C3_ + 2 * C_ + h * D_;
  const u16* qbase = qkv + (size_t)(b * T_ + qrow0w) * C3_ + h * D_;

  bf16x8 qf0 = *(const bf16x8*)(qbase + (size_t)cc * C3_ + qg * 8);
  bf16x8 qf1 = *(const bf16x8*)(qbase + (size_t)cc * C3_ + 32 + qg * 8);

  const u16* kg = kbase + (size_t)((tid >> 7) * 16 + (tid & 15)) * C3_ +
                  ((tid >> 6) & 1) * 32 + ((tid >> 4) & 3) * 8;
  const u16* vg = vbase + (size_t)(((tid >> 6) & 1) * 32 + ((tid >> 4) & 3) * 8) * C3_ +
                  (tid >> 7) * 16 + (tid & 15);

  int4 kpref = *(const int4*)kg;
  u16 vp[8];
#pragma unroll
  for (int e = 0; e < 8; ++e) vp[e] = vg[(size_t)e * C3_];

  float m_r = -1e30f, l_r = 0.f;           // per-lane: q = qabs
  f32x4 o[4];
#pragma unroll
  for (int db = 0; db < 4; ++db) o[db] = (f32x4){0.f, 0.f, 0.f, 0.f};

  for (int j = 0; j < jn; ++j) {
    __syncthreads();
    Ks4[tid] = kpref;
    {
      int4 vv; u16* vvp = (u16*)&vv;
#pragma unroll
      for (int e = 0; e < 8; ++e) vvp[e] = vp[e];
      Vs4[tid] = vv;
    }
    __syncthreads();

    if (j + 1 < jn) {
      const u16* kg2 = kg + (size_t)(j + 1) * 64 * C3_;
      kpref = *(const int4*)kg2;
      const u16* vg2 = vg + (size_t)(j + 1) * 64 * C3_;
#pragma unroll
      for (int e = 0; e < 8; ++e) vp[e] = vg2[(size_t)e * C3_];
    }

    if (j > qtile) continue;

    // ---- S^T = K Q^T : lane holds S[kv = kb*16+qg*4+r][q = cc] ----
    __builtin_amdgcn_s_setprio(1);
    f32x4 s[4];
#pragma unroll
    for (int kb = 0; kb < 4; ++kb) {
      bf16x8 kf0 = *(const bf16x8*)(Ks4 + kb * 128 + lane);
      bf16x8 kf1 = *(const bf16x8*)(Ks4 + kb * 128 + 64 + lane);
      f32x4 z = (f32x4){0.f, 0.f, 0.f, 0.f};
      z = __builtin_amdgcn_mfma_f32_16x16x32_bf16(kf0, qf0, z, 0, 0, 0);
      z = __builtin_amdgcn_mfma_f32_16x16x32_bf16(kf1, qf1, z, 0, 0, 0);
      s[kb] = z;
    }
    __builtin_amdgcn_s_setprio(0);

    if (j == qtile) {                      // diagonal causal mask
#pragma unroll
      for (int kb = 0; kb < 4; ++kb)
#pragma unroll
        for (int r = 0; r < 4; ++r)
          if ((j * 64 + kb * 16 + qg * 4 + r) > qabs) s[kb][r] = -1e30f;
    }

    // ---- in-lane row max + 2 cross-lane steps ----
    float mx = s[0][0];
#pragma unroll
    for (int kb = 0; kb < 4; ++kb)
#pragma unroll
      for (int r = 0; r < 4; ++r) mx = fmaxf(mx, s[kb][r]);
    mx = fmaxf(mx, __shfl_xor(mx, 16));
    mx = fmaxf(mx, __shfl_xor(mx, 32));

    // defer-rescale: only pay when some row max grew
    if (!__all(mx <= m_r)) {
      float mn = fmaxf(m_r, mx);
      float al = exp2f(m_r - mn);
      m_r = mn;
      l_r *= al;
      float alq[4];
#pragma unroll
      for (int r = 0; r < 4; ++r)
        alq[r] = __shfl(al, (lane & 48) | (qg * 4 + r));
#pragma unroll
      for (int db = 0; db < 4; ++db)
#pragma unroll
        for (int r = 0; r < 4; ++r) o[db][r] *= alq[r];
    }

    // ---- p = exp2(s - m), per-lane partial l ----
    float lsum = 0.f;
#pragma unroll
    for (int kb = 0; kb < 4; ++kb)
#pragma unroll
      for (int r = 0; r < 4; ++r) {
        float p = exp2f(s[kb][r] - m_r);
        s[kb][r] = p;
        lsum += p;
      }
    l_r += lsum;

    // ---- packed P -> per-wave LDS (consecutive kv are lane-local) ----
    {
      char* myPb = (char*)(Ps4 + wq * 128);
#pragma unroll
      for (int kb = 0; kb < 4; ++kb) {
        unsigned plo, phi;
        asm("v_cvt_pk_bf16_f32 %0, %1, %2" : "=v"(plo) : "v"(s[kb][0]), "v"(s[kb][1]));
        asm("v_cvt_pk_bf16_f32 %0, %1, %2" : "=v"(phi) : "v"(s[kb][2]), "v"(s[kb][3]));
        const int kv0 = kb * 16 + qg * 4;
        const int g = ((kv0 >> 5) << 6) + (((kv0 >> 3) & 3) << 4) + cc;
        uint2 pk; pk.x = plo; pk.y = phi;
        *(uint2*)(myPb + g * 16 + (kv0 & 7) * 2) = pk;
      }
    }

    // ---- O += P V : 8 MFMAs ----
    __builtin_amdgcn_s_setprio(1);
#pragma unroll
    for (int ks = 0; ks < 2; ++ks) {
      bf16x8 pf = *(const bf16x8*)(Ps4 + wq * 128 + ks * 64 + lane);
#pragma unroll
      for (int db = 0; db < 4; ++db) {
        bf16x8 vf = *(const bf16x8*)(Vs4 + db * 128 + ks * 64 + lane);
        o[db] = __builtin_amdgcn_mfma_f32_16x16x32_bf16(pf, vf, o[db], 0, 0, 0);
      }
    }
    __builtin_amdgcn_s_setprio(0);
  }

  // ---- epilogue: reduce l across the 4 lane-groups, redistribute, write ----
  float ls = l_r;
  ls += __shfl_xor(ls, 16);
  ls += __shfl_xor(ls, 32);
  float linv_l = 1.0f / ls;
  float linv[4];
#pragma unroll
  for (int r = 0; r < 4; ++r)
    linv[r] = __shfl(linv_l, (lane & 48) | (qg * 4 + r));

  u16* yb = yout + (size_t)(b * T_ + qrow0w + qg * 4) * C_ + h * D_ + cc;
#pragma unroll
  for (int db = 0; db < 4; ++db)
#pragma unroll
    for (int r = 0; r < 4; ++r)
      yb[(size_t)r * C_ + db * 16] = f2bf(o[db][r] * linv[r]);
}

// ---------------------------------------------------------------------------
extern "C" void kernel_launch(void* const* d_in, const int* in_sizes, int n_in,
                              void* d_out, int out_size, void* d_ws, size_t ws_size,
                              hipStream_t stream) {
  const float* x      = (const float*)d_in[0];
  const float* w_attn = (const float*)d_in[1];
  const float* b_attn = (const float*)d_in[2];
  const float* w_proj = (const float*)d_in[3];
  const float* b_proj = (const float*)d_in[4];
  float* out = (float*)d_out;

  char* ws = (char*)d_ws;
  u16* xb  = (u16*)(ws);                          // 16 MB
  u16* waT = (u16*)(ws + 16777216);               //  6 MB  [3072][1024]
  u16* wpT = (u16*)(ws + 23068672);               //  2 MB  [1024][1024]
  u16* qkv = (u16*)(ws + 25165824);               // 48 MB  [8192][3072]
  u16* yb  = (u16*)(ws + 75497472);               // 16 MB  [8192][1024]

  cvt_bf16<<<4096, 256, 0, stream>>>(x, xb, (B_ * T_ * C_) / 8);
  transcvt<<<dim3(C3_ / 64, C_ / 16), 256, 0, stream>>>(w_attn, waT, C_, C3_);
  transcvt<<<dim3(C_ / 64, C_ / 16), 256, 0, stream>>>(w_proj, wpT, C_, C_);

  // q columns pre-scaled by (1/sqrt(D)) * log2(e) for exp2-domain softmax
  gemm_bf16<u16><<<dim3(C3_ / 128, (B_ * T_) / 128), 256, 0, stream>>>(
      xb, waT, b_attn, qkv, B_ * T_, C3_, C_, C_);

  attn_mfma<<<dim3(16 * H_ * B_), 512, 0, stream>>>(qkv, yb);

  gemm_bf16<float><<<dim3(C_ / 128, (B_ * T_) / 128), 256, 0, stream>>>(
      yb, wpT, b_proj, out, B_ * T_, C_, C_, 0);
}

// Round 6
// 248.069 us; speedup vs baseline: 10.0027x; 1.0468x over previous
//
#include <hip/hip_runtime.h>
#include <hip/hip_bf16.h>

#define B_  4
#define T_  2048
#define C_  1024
#define H_  16
#define D_  64
#define C3_ 3072

typedef __attribute__((ext_vector_type(8))) short bf16x8;
typedef __attribute__((ext_vector_type(4))) float f32x4;
typedef unsigned short u16;

#define CSCALE 0.1803368801111204f   /* (1/8) * log2(e) */

__device__ __forceinline__ u16 f2bf(float f) {
  union { float f; unsigned int u; } v; v.f = f;
  unsigned int r = (v.u + 0x7FFFu + ((v.u >> 16) & 1u)) >> 16;
  return (u16)r;
}

__device__ __forceinline__ void gload16(void* l, const void* g) {
  __builtin_amdgcn_global_load_lds(
      (const __attribute__((address_space(1))) unsigned int*)g,
      (__attribute__((address_space(3))) unsigned int*)l, 16, 0, 0);
}

// ---------------------------------------------------------------------------
__global__ __launch_bounds__(256)
void cvt_bf16(const float* __restrict__ in, u16* __restrict__ out, int n8) {
  int i = blockIdx.x * 256 + threadIdx.x;
  if (i >= n8) return;
  float4 a = *(const float4*)(in + (size_t)i * 8);
  float4 b = *(const float4*)(in + (size_t)i * 8 + 4);
  ushort4 lo, hi;
  lo.x = f2bf(a.x); lo.y = f2bf(a.y); lo.z = f2bf(a.z); lo.w = f2bf(a.w);
  hi.x = f2bf(b.x); hi.y = f2bf(b.y); hi.z = f2bf(b.z); hi.w = f2bf(b.w);
  *(ushort4*)(out + (size_t)i * 8) = lo;
  *(ushort4*)(out + (size_t)i * 8 + 4) = hi;
}

__global__ __launch_bounds__(256)
void transcvt(const float* __restrict__ w, u16* __restrict__ wT, int K, int N) {
  int n  = blockIdx.x * 64 + (threadIdx.x & 63);
  int k0 = blockIdx.y * 16 + (threadIdx.x >> 6) * 4;
  float v0 = w[(size_t)(k0 + 0) * N + n];
  float v1 = w[(size_t)(k0 + 1) * N + n];
  float v2 = w[(size_t)(k0 + 2) * N + n];
  float v3 = w[(size_t)(k0 + 3) * N + n];
  ushort4 o; o.x = f2bf(v0); o.y = f2bf(v1); o.z = f2bf(v2); o.w = f2bf(v3);
  *(ushort4*)(wT + (size_t)n * K + k0) = o;
}

// ---------------------------------------------------------------------------
// V transpose: qkv v-columns [t][d] -> vT[bh][d][t].  Coalesced reads
// (lanes span d), 16B stores along t.
// grid: 64 bh * 64 tchunk blocks, 256 threads.
// ---------------------------------------------------------------------------
__global__ __launch_bounds__(256)
void vtrans(const u16* __restrict__ qkv, u16* __restrict__ vT) {
  const int bid = blockIdx.x;
  const int bh = bid >> 6, tc = bid & 63;
  const int d = threadIdx.x & 63, t4 = threadIdx.x >> 6;
  const int t8 = tc * 4 + t4;            // granule index along t (8 t each)
  const int b = bh >> 4, h = bh & 15;
  const u16* src = qkv + (size_t)(b * T_ + t8 * 8) * C3_ + 2 * C_ + h * 64 + d;
  union { u16 a[8]; int4 v; } u;
#pragma unroll
  for (int e = 0; e < 8; ++e) u.a[e] = src[(size_t)e * C3_];
  *(int4*)(vT + ((size_t)bh * 64 + d) * T_ + t8 * 8) = u.v;
}

// ---------------------------------------------------------------------------
// bf16 MFMA GEMM (m97 structure), unchanged.
// ---------------------------------------------------------------------------
template <typename OutT>
__global__ __launch_bounds__(256)
void gemm_bf16(const u16* __restrict__ A, const u16* __restrict__ Bt,
               const float* __restrict__ bias, OutT* __restrict__ C,
               int M, int N, int K, int qscale_cols) {
  __shared__ int4 As4[512];
  __shared__ int4 Bs4[512];

  const int tid  = threadIdx.x;
  const int lane = tid & 63;
  const int wid  = tid >> 6;
  const int wr   = wid >> 1, wc = wid & 1;
  const int row0 = blockIdx.y * 128, col0 = blockIdx.x * 128;

  f32x4 acc[4][4];
#pragma unroll
  for (int m = 0; m < 4; ++m)
#pragma unroll
    for (int n = 0; n < 4; ++n) acc[m][n] = (f32x4){0.f, 0.f, 0.f, 0.f};

  const int L1 = tid, L2 = 256 + tid;
  const u16* a1 = A + (size_t)(row0 + ((L1 >> 6) * 16) + (L1 & 15)) * K + ((L1 >> 4) & 3) * 8;
  const u16* a2 = A + (size_t)(row0 + ((L2 >> 6) * 16) + (L2 & 15)) * K + ((L2 >> 4) & 3) * 8;
  const u16* b1 = Bt + (size_t)(col0 + ((L1 >> 6) * 16) + (L1 & 15)) * K + ((L1 >> 4) & 3) * 8;
  const u16* b2 = Bt + (size_t)(col0 + ((L2 >> 6) * 16) + (L2 & 15)) * K + ((L2 >> 4) & 3) * 8;

  const int nk = K >> 5;
  for (int kt = 0; kt < nk; ++kt) {
    __syncthreads();
    gload16(As4 + wid * 64, a1);
    gload16(As4 + 256 + wid * 64, a2);
    gload16(Bs4 + wid * 64, b1);
    gload16(Bs4 + 256 + wid * 64, b2);
    a1 += 32; a2 += 32; b1 += 32; b2 += 32;
    __syncthreads();

    bf16x8 a[4], b[4];
#pragma unroll
    for (int m = 0; m < 4; ++m)
      a[m] = *(const bf16x8*)(As4 + (wr * 4 + m) * 64 + lane);
#pragma unroll
    for (int n = 0; n < 4; ++n)
      b[n] = *(const bf16x8*)(Bs4 + (wc * 4 + n) * 64 + lane);
#pragma unroll
    for (int m = 0; m < 4; ++m)
#pragma unroll
      for (int n = 0; n < 4; ++n)
        acc[m][n] = __builtin_amdgcn_mfma_f32_16x16x32_bf16(a[m], b[n], acc[m][n], 0, 0, 0);
  }

  const int cc = lane & 15, qg = lane >> 4;
#pragma unroll
  for (int m = 0; m < 4; ++m) {
#pragma unroll
    for (int n = 0; n < 4; ++n) {
      const int gc = col0 + wc * 64 + n * 16 + cc;
      const float bv = bias[gc];
      const float sc = (gc < qscale_cols) ? CSCALE : 1.0f;
#pragma unroll
      for (int r = 0; r < 4; ++r) {
        const int gr = row0 + wr * 64 + m * 16 + qg * 4 + r;
        float val = (acc[m][n][r] + bv) * sc;
        if constexpr (sizeof(OutT) == 2)
          ((u16*)C)[(size_t)gr * N + gc] = f2bf(val);
        else
          ((float*)C)[(size_t)gr * N + gc] = val;
      }
    }
  }
}

// ---------------------------------------------------------------------------
// Flash attention v6: QBLK=32 per wave (two 16-row halves sharing all K/V
// fragment reads). Block = 8 waves: waves 0-3 -> 128-row tile ip, waves 4-7
// -> tile 15-ip (causal pairing). K from qkv, V from pre-transposed vT
// (single b128 prefetch each). Swapped QK^T, exp2 softmax, defer-rescale.
// ---------------------------------------------------------------------------
__global__ __launch_bounds__(512, 4)
void attn_mfma(const u16* __restrict__ qkv, const u16* __restrict__ vT,
               u16* __restrict__ yout) {
  __shared__ int4 Ks4[512];        // 8 KB  K granules
  __shared__ int4 Vs4[512];        // 8 KB  V^T granules
  __shared__ int4 Ps4[2048];       // 32 KB per-wave P (2 halves x 2KB)

  const int n   = blockIdx.x;
  const int xcd = n & 7, t = n >> 3;
  const int bh  = xcd * 8 + (t >> 3);
  const int ip  = t & 7;                    // pair index 0..7
  const int b   = bh >> 4, h = bh & 15;

  const int tid = threadIdx.x;
  const int lane = tid & 63, wq = tid >> 6;
  const int sub = wq & 3;
  const int cc = lane & 15, qg = lane >> 4;

  const int qt128 = (wq < 4) ? ip : (15 - ip);   // 128-row tile
  const int qrow0 = qt128 * 128 + sub * 32;      // wave's 32 q-rows
  const int diag  = qt128 * 2 + (sub >> 1);      // diagonal 64-kv tile
  const int jn    = 32 - 2 * ip;                 // tiles staged by this block

  const u16* kbase = qkv + (size_t)b * T_ * C3_ + C_ + h * D_;
  const u16* vtb   = vT + (size_t)bh * D_ * T_;

  // Q fragments for both 16-row halves
  bf16x8 qf[2][2];
#pragma unroll
  for (int hf = 0; hf < 2; ++hf) {
    const u16* qb = qkv + (size_t)(b * T_ + qrow0 + hf * 16 + cc) * C3_ + h * D_;
    qf[hf][0] = *(const bf16x8*)(qb + qg * 8);
    qf[hf][1] = *(const bf16x8*)(qb + 32 + qg * 8);
  }

  // staging sources (granule = tid)
  const u16* kg = kbase + (size_t)((tid >> 7) * 16 + (tid & 15)) * C3_ +
                  ((tid >> 6) & 1) * 32 + ((tid >> 4) & 3) * 8;
  const u16* vg = vtb + (size_t)((tid >> 7) * 16 + (tid & 15)) * T_ +
                  ((tid >> 6) & 1) * 32 + ((tid >> 4) & 3) * 8;

  int4 kpref = *(const int4*)kg;
  int4 vpref = *(const int4*)vg;

  float m_r[2] = {-1e30f, -1e30f}, l_r[2] = {0.f, 0.f};
  f32x4 o[2][4];
#pragma unroll
  for (int hf = 0; hf < 2; ++hf)
#pragma unroll
    for (int db = 0; db < 4; ++db) o[hf][db] = (f32x4){0.f, 0.f, 0.f, 0.f};

  for (int j = 0; j < jn; ++j) {
    __syncthreads();                    // prev tile's reads complete
    Ks4[tid] = kpref;
    Vs4[tid] = vpref;
    __syncthreads();                    // tile ready
    if (j + 1 < jn) {                   // prefetch next tile (hidden)
      kpref = *(const int4*)(kg + (size_t)(j + 1) * 64 * C3_);
      vpref = *(const int4*)(vg + (j + 1) * 64);
    }
    if (j > diag) continue;

    // ---- S^T = K Q^T, both halves share kf reads: 16 MFMAs ----
    __builtin_amdgcn_s_setprio(1);
    f32x4 s[2][4];
#pragma unroll
    for (int kb = 0; kb < 4; ++kb) {
      bf16x8 kf0 = *(const bf16x8*)(Ks4 + kb * 128 + lane);
      bf16x8 kf1 = *(const bf16x8*)(Ks4 + kb * 128 + 64 + lane);
#pragma unroll
      for (int hf = 0; hf < 2; ++hf) {
        f32x4 z = (f32x4){0.f, 0.f, 0.f, 0.f};
        z = __builtin_amdgcn_mfma_f32_16x16x32_bf16(kf0, qf[hf][0], z, 0, 0, 0);
        z = __builtin_amdgcn_mfma_f32_16x16x32_bf16(kf1, qf[hf][1], z, 0, 0, 0);
        s[hf][kb] = z;
      }
    }
    __builtin_amdgcn_s_setprio(0);

    if (j == diag) {                    // diagonal causal mask
#pragma unroll
      for (int hf = 0; hf < 2; ++hf) {
        const int qabs = qrow0 + hf * 16 + cc;
#pragma unroll
        for (int kb = 0; kb < 4; ++kb)
#pragma unroll
          for (int r = 0; r < 4; ++r)
            if ((j * 64 + kb * 16 + qg * 4 + r) > qabs) s[hf][kb][r] = -1e30f;
      }
    }

    // ---- softmax per half (in-lane, 2 cross-lane steps) ----
#pragma unroll
    for (int hf = 0; hf < 2; ++hf) {
      float mx = s[hf][0][0];
#pragma unroll
      for (int kb = 0; kb < 4; ++kb)
#pragma unroll
        for (int r = 0; r < 4; ++r) mx = fmaxf(mx, s[hf][kb][r]);
      mx = fmaxf(mx, __shfl_xor(mx, 16));
      mx = fmaxf(mx, __shfl_xor(mx, 32));

      if (!__all(mx <= m_r[hf])) {
        float mn = fmaxf(m_r[hf], mx);
        float al = exp2f(m_r[hf] - mn);
        m_r[hf] = mn;
        l_r[hf] *= al;
        float alq[4];
#pragma unroll
        for (int r = 0; r < 4; ++r)
          alq[r] = __shfl(al, (lane & 48) | (qg * 4 + r));
#pragma unroll
        for (int db = 0; db < 4; ++db)
#pragma unroll
          for (int r = 0; r < 4; ++r) o[hf][db][r] *= alq[r];
      }

      float lsum = 0.f;
#pragma unroll
      for (int kb = 0; kb < 4; ++kb)
#pragma unroll
        for (int r = 0; r < 4; ++r) {
          float p = exp2f(s[hf][kb][r] - m_r[hf]);
          s[hf][kb][r] = p;
          lsum += p;
        }
      l_r[hf] += lsum;

      // packed P -> per-wave-half LDS
      char* myPb = (char*)(Ps4 + wq * 256 + hf * 128);
#pragma unroll
      for (int kb = 0; kb < 4; ++kb) {
        unsigned plo, phi;
        asm("v_cvt_pk_bf16_f32 %0, %1, %2" : "=v"(plo) : "v"(s[hf][kb][0]), "v"(s[hf][kb][1]));
        asm("v_cvt_pk_bf16_f32 %0, %1, %2" : "=v"(phi) : "v"(s[hf][kb][2]), "v"(s[hf][kb][3]));
        const int kv0 = kb * 16 + qg * 4;
        const int g = ((kv0 >> 5) << 6) + (((kv0 >> 3) & 3) << 4) + cc;
        uint2 pk; pk.x = plo; pk.y = phi;
        *(uint2*)(myPb + g * 16 + (kv0 & 7) * 2) = pk;
      }
    }

    // ---- O += P V, both halves share vf reads: 16 MFMAs ----
    bf16x8 pa[2][2];
#pragma unroll
    for (int hf = 0; hf < 2; ++hf)
#pragma unroll
      for (int ks = 0; ks < 2; ++ks)
        pa[hf][ks] = *(const bf16x8*)(Ps4 + wq * 256 + hf * 128 + ks * 64 + lane);
    __builtin_amdgcn_s_setprio(1);
#pragma unroll
    for (int db = 0; db < 4; ++db) {
#pragma unroll
      for (int ks = 0; ks < 2; ++ks) {
        bf16x8 vf = *(const bf16x8*)(Vs4 + db * 128 + ks * 64 + lane);
        o[0][db] = __builtin_amdgcn_mfma_f32_16x16x32_bf16(pa[0][ks], vf, o[0][db], 0, 0, 0);
        o[1][db] = __builtin_amdgcn_mfma_f32_16x16x32_bf16(pa[1][ks], vf, o[1][db], 0, 0, 0);
      }
    }
    __builtin_amdgcn_s_setprio(0);
  }

  // ---- epilogue per half ----
#pragma unroll
  for (int hf = 0; hf < 2; ++hf) {
    float ls = l_r[hf];
    ls += __shfl_xor(ls, 16);
    ls += __shfl_xor(ls, 32);
    float linv_l = 1.0f / ls;
    float linv[4];
#pragma unroll
    for (int r = 0; r < 4; ++r)
      linv[r] = __shfl(linv_l, (lane & 48) | (qg * 4 + r));

    u16* yb = yout + (size_t)(b * T_ + qrow0 + hf * 16 + qg * 4) * C_ + h * D_ + cc;
#pragma unroll
    for (int db = 0; db < 4; ++db)
#pragma unroll
      for (int r = 0; r < 4; ++r)
        yb[(size_t)r * C_ + db * 16] = f2bf(o[hf][db][r] * linv[r]);
  }
}

// ---------------------------------------------------------------------------
extern "C" void kernel_launch(void* const* d_in, const int* in_sizes, int n_in,
                              void* d_out, int out_size, void* d_ws, size_t ws_size,
                              hipStream_t stream) {
  const float* x      = (const float*)d_in[0];
  const float* w_attn = (const float*)d_in[1];
  const float* b_attn = (const float*)d_in[2];
  const float* w_proj = (const float*)d_in[3];
  const float* b_proj = (const float*)d_in[4];
  float* out = (float*)d_out;

  char* ws = (char*)d_ws;
  u16* xb  = (u16*)(ws);                          // 16 MB
  u16* waT = (u16*)(ws + 16777216);               //  6 MB  [3072][1024]
  u16* wpT = (u16*)(ws + 23068672);               //  2 MB  [1024][1024]
  u16* qkv = (u16*)(ws + 25165824);               // 48 MB  [8192][3072]
  u16* yb  = (u16*)(ws + 75497472);               // 16 MB  [8192][1024]
  u16* vT  = (u16*)(ws + 92274688);               // 16 MB  [64][64][2048]

  cvt_bf16<<<4096, 256, 0, stream>>>(x, xb, (B_ * T_ * C_) / 8);
  transcvt<<<dim3(C3_ / 64, C_ / 16), 256, 0, stream>>>(w_attn, waT, C_, C3_);
  transcvt<<<dim3(C_ / 64, C_ / 16), 256, 0, stream>>>(w_proj, wpT, C_, C_);

  // q columns pre-scaled by (1/sqrt(D)) * log2(e) for exp2-domain softmax
  gemm_bf16<u16><<<dim3(C3_ / 128, (B_ * T_) / 128), 256, 0, stream>>>(
      xb, waT, b_attn, qkv, B_ * T_, C3_, C_, C_);

  vtrans<<<4096, 256, 0, stream>>>(qkv, vT);

  attn_mfma<<<dim3(8 * H_ * B_), 512, 0, stream>>>(qkv, vT, yb);

  gemm_bf16<float><<<dim3(C_ / 128, (B_ * T_) / 128), 256, 0, stream>>>(
      yb, wpT, b_proj, out, B_ * T_, C_, C_, 0);
}

// Round 8
// 224.338 us; speedup vs baseline: 11.0608x; 1.1058x over previous
//
#include <hip/hip_runtime.h>
#include <hip/hip_bf16.h>

#define B_  4
#define T_  2048
#define C_  1024
#define H_  16
#define D_  64
#define C3_ 3072

typedef __attribute__((ext_vector_type(8))) short bf16x8;
typedef __attribute__((ext_vector_type(4))) float f32x4;
typedef unsigned short u16;

#define CSCALE 0.1803368801111204f   /* (1/8) * log2(e) */

__device__ __forceinline__ u16 f2bf(float f) {
  union { float f; unsigned int u; } v; v.f = f;
  unsigned int r = (v.u + 0x7FFFu + ((v.u >> 16) & 1u)) >> 16;
  return (u16)r;
}

__device__ __forceinline__ void gload16(void* l, const void* g) {
  __builtin_amdgcn_global_load_lds(
      (const __attribute__((address_space(1))) unsigned int*)g,
      (__attribute__((address_space(3))) unsigned int*)l, 16, 0, 0);
}

// ---------------------------------------------------------------------------
__global__ __launch_bounds__(256)
void cvt_bf16(const float* __restrict__ in, u16* __restrict__ out, int n8) {
  int i = blockIdx.x * 256 + threadIdx.x;
  if (i >= n8) return;
  float4 a = *(const float4*)(in + (size_t)i * 8);
  float4 b = *(const float4*)(in + (size_t)i * 8 + 4);
  ushort4 lo, hi;
  lo.x = f2bf(a.x); lo.y = f2bf(a.y); lo.z = f2bf(a.z); lo.w = f2bf(a.w);
  hi.x = f2bf(b.x); hi.y = f2bf(b.y); hi.z = f2bf(b.z); hi.w = f2bf(b.w);
  *(ushort4*)(out + (size_t)i * 8) = lo;
  *(ushort4*)(out + (size_t)i * 8 + 4) = hi;
}

__global__ __launch_bounds__(256)
void transcvt(const float* __restrict__ w, u16* __restrict__ wT, int K, int N) {
  int n  = blockIdx.x * 64 + (threadIdx.x & 63);
  int k0 = blockIdx.y * 16 + (threadIdx.x >> 6) * 4;
  float v0 = w[(size_t)(k0 + 0) * N + n];
  float v1 = w[(size_t)(k0 + 1) * N + n];
  float v2 = w[(size_t)(k0 + 2) * N + n];
  float v3 = w[(size_t)(k0 + 3) * N + n];
  ushort4 o; o.x = f2bf(v0); o.y = f2bf(v1); o.z = f2bf(v2); o.w = f2bf(v3);
  *(ushort4*)(wT + (size_t)n * K + k0) = o;
}

__global__ __launch_bounds__(256)
void vtrans(const u16* __restrict__ qkv, u16* __restrict__ vT) {
  const int bid = blockIdx.x;
  const int bh = bid >> 6, tc = bid & 63;
  const int d = threadIdx.x & 63, t4 = threadIdx.x >> 6;
  const int t8 = tc * 4 + t4;
  const int b = bh >> 4, h = bh & 15;
  const u16* src = qkv + (size_t)(b * T_ + t8 * 8) * C3_ + 2 * C_ + h * 64 + d;
  union { u16 a[8]; int4 v; } u;
#pragma unroll
  for (int e = 0; e < 8; ++e) u.a[e] = src[(size_t)e * C3_];
  *(int4*)(vT + ((size_t)bh * 64 + d) * T_ + t8 * 8) = u.v;
}

// ---------------------------------------------------------------------------
// 256x256 8-phase GEMM (T3+T4+T5), RACE-FIXED stage schedule.
// Region liveness (buf b): B fully read by ph2-close, A fully read by
// ph3-close (A-half = wr, so whole A live through ph3).  Stages:
//   ph1: t1.A1->buf1 | ph3: t2.B0->buf0 | ph4: t2.B1+A0->buf0, vmcnt(6)
//   ph5: t2.A1->buf0 | ph7: t3.B0->buf1 | ph8: t3.B1+A0->buf1, vmcnt(6)
// vmcnt(6) at ph4 drains t1.A1 (buf1 complete for ph5); at ph8 drains
// t2.A1 (buf0 complete for next ph1).
// ---------------------------------------------------------------------------
template <typename OutT>
__global__ __launch_bounds__(512, 2)
void gemm256(const u16* __restrict__ A, const u16* __restrict__ Bt,
             const float* __restrict__ bias, OutT* __restrict__ C,
             int M, int N, int K, int qscale_cols) {
  // granule g in [0,2048) per operand: sub=g>>7 (16-row band),
  // q=(g>>4)&7 (8-bf16 k-slot), c=g&15 (row within band)
  __shared__ int4 lds[8192];   // 128 KiB: [buf(2)][A 0-2047 | B 2048-4095]

  const int tid = threadIdx.x, lane = tid & 63, wid = tid >> 6;
  const int wr = wid >> 2, wc = wid & 3;           // 2M x 4N waves
  const int row0 = blockIdx.y * 256, col0 = blockIdx.x * 256;

  f32x4 acc[8][4];
#pragma unroll
  for (int m = 0; m < 8; ++m)
#pragma unroll
    for (int nf = 0; nf < 4; ++nf) acc[m][nf] = (f32x4){0.f, 0.f, 0.f, 0.f};

  const u16* pA[2][2]; const u16* pB[2][2];
#pragma unroll
  for (int h = 0; h < 2; ++h)
#pragma unroll
    for (int i = 0; i < 2; ++i) {
      int g = h * 1024 + i * 512 + tid;
      int rr = ((g >> 7) << 4) + (g & 15), ko = ((g >> 4) & 7) * 8;
      pA[h][i] = A + (size_t)(row0 + rr) * K + ko;
      pB[h][i] = Bt + (size_t)(col0 + rr) * K + ko;
    }

  auto stage = [&](int t, int isA, int h, int buf) {
    const u16* p0 = (isA ? pA[h][0] : pB[h][0]) + t * 64;
    const u16* p1 = (isA ? pA[h][1] : pB[h][1]) + t * 64;
    int4* d = &lds[buf * 4096 + (isA ? 0 : 2048) + h * 1024 + wid * 64];
    gload16(d, p0);
    gload16(d + 512, p1);
  };
  auto rdA = [&](int f, int kk, int buf) {
    return *(const bf16x8*)&lds[buf * 4096 + (wr * 8 + f) * 128 + kk * 64 + lane];
  };
  auto rdB = [&](int nf, int kk, int buf) {
    return *(const bf16x8*)&lds[buf * 4096 + 2048 + (wc * 4 + nf) * 128 + kk * 64 + lane];
  };

  const int nk = K >> 6, nit = nk >> 1;   // K=1024 -> nk=16, nit=8

  // ---- prologue: t0 {A0,A1,B0,B1}, t1 {B0,B1,A0}; drain t0, keep t1 ----
  stage(0, 1, 0, 0); stage(0, 1, 1, 0); stage(0, 0, 0, 0); stage(0, 0, 1, 0);
  stage(1, 0, 0, 1); stage(1, 0, 1, 1); stage(1, 1, 0, 1);
  asm volatile("s_waitcnt vmcnt(6)" ::: "memory");
  __builtin_amdgcn_s_barrier();

  for (int it = 0; it < nit; ++it) {
    const int t1g = 2 * it + 1, t2g = t1g + 1, t3g = t1g + 2;
    bf16x8 a0[4][2], a1[4][2], b0[2][2], b1[2][2];

    // ===== K-tile 2it (buf0) =====
    // ph1: read a0+b0; stage t1.A1 -> buf1 (inactive); MFMA (M0,N0)
#pragma unroll
    for (int m = 0; m < 4; ++m) { a0[m][0] = rdA(m, 0, 0); a0[m][1] = rdA(m, 1, 0); }
#pragma unroll
    for (int nf = 0; nf < 2; ++nf) { b0[nf][0] = rdB(nf, 0, 0); b0[nf][1] = rdB(nf, 1, 0); }
    stage(t1g, 1, 1, 1);
    __builtin_amdgcn_s_barrier();
    __builtin_amdgcn_s_setprio(1);
#pragma unroll
    for (int m = 0; m < 4; ++m)
#pragma unroll
      for (int nf = 0; nf < 2; ++nf) {
        acc[m][nf] = __builtin_amdgcn_mfma_f32_16x16x32_bf16(a0[m][0], b0[nf][0], acc[m][nf], 0, 0, 0);
        acc[m][nf] = __builtin_amdgcn_mfma_f32_16x16x32_bf16(a0[m][1], b0[nf][1], acc[m][nf], 0, 0, 0);
      }
    __builtin_amdgcn_s_setprio(0);
    __builtin_amdgcn_s_barrier();

    // ph2: read b1; no stage; MFMA (M0,N1)
#pragma unroll
    for (int nf = 0; nf < 2; ++nf) { b1[nf][0] = rdB(2 + nf, 0, 0); b1[nf][1] = rdB(2 + nf, 1, 0); }
    __builtin_amdgcn_s_barrier();
    __builtin_amdgcn_s_setprio(1);
#pragma unroll
    for (int m = 0; m < 4; ++m)
#pragma unroll
      for (int nf = 0; nf < 2; ++nf) {
        acc[m][2 + nf] = __builtin_amdgcn_mfma_f32_16x16x32_bf16(a0[m][0], b1[nf][0], acc[m][2 + nf], 0, 0, 0);
        acc[m][2 + nf] = __builtin_amdgcn_mfma_f32_16x16x32_bf16(a0[m][1], b1[nf][1], acc[m][2 + nf], 0, 0, 0);
      }
    __builtin_amdgcn_s_setprio(0);
    __builtin_amdgcn_s_barrier();

    // ph3: read a1; stage t2.B0 -> buf0 (B region dead since ph2); MFMA (M1,N1)
#pragma unroll
    for (int m = 0; m < 4; ++m) { a1[m][0] = rdA(4 + m, 0, 0); a1[m][1] = rdA(4 + m, 1, 0); }
    if (t2g < nk) stage(t2g, 0, 0, 0);
    __builtin_amdgcn_s_barrier();
    __builtin_amdgcn_s_setprio(1);
#pragma unroll
    for (int m = 0; m < 4; ++m)
#pragma unroll
      for (int nf = 0; nf < 2; ++nf) {
        acc[4 + m][2 + nf] = __builtin_amdgcn_mfma_f32_16x16x32_bf16(a1[m][0], b1[nf][0], acc[4 + m][2 + nf], 0, 0, 0);
        acc[4 + m][2 + nf] = __builtin_amdgcn_mfma_f32_16x16x32_bf16(a1[m][1], b1[nf][1], acc[4 + m][2 + nf], 0, 0, 0);
      }
    __builtin_amdgcn_s_setprio(0);
    __builtin_amdgcn_s_barrier();

    // ph4: stage t2.B1 + t2.A0 (A region dead since ph3); vmcnt; MFMA (M1,N0)
    if (t2g < nk) {
      stage(t2g, 0, 1, 0);
      stage(t2g, 1, 0, 0);
      asm volatile("s_waitcnt vmcnt(6)" ::: "memory");   // drains t1.A1
    } else {
      asm volatile("s_waitcnt vmcnt(0)" ::: "memory");
    }
    __builtin_amdgcn_s_barrier();
    __builtin_amdgcn_s_setprio(1);
#pragma unroll
    for (int m = 0; m < 4; ++m)
#pragma unroll
      for (int nf = 0; nf < 2; ++nf) {
        acc[4 + m][nf] = __builtin_amdgcn_mfma_f32_16x16x32_bf16(a1[m][0], b0[nf][0], acc[4 + m][nf], 0, 0, 0);
        acc[4 + m][nf] = __builtin_amdgcn_mfma_f32_16x16x32_bf16(a1[m][1], b0[nf][1], acc[4 + m][nf], 0, 0, 0);
      }
    __builtin_amdgcn_s_setprio(0);
    __builtin_amdgcn_s_barrier();

    // ===== K-tile 2it+1 (buf1) =====
    // ph5: read a0+b0 (buf1); stage t2.A1 -> buf0 (inactive); MFMA (M0,N0)
#pragma unroll
    for (int m = 0; m < 4; ++m) { a0[m][0] = rdA(m, 0, 1); a0[m][1] = rdA(m, 1, 1); }
#pragma unroll
    for (int nf = 0; nf < 2; ++nf) { b0[nf][0] = rdB(nf, 0, 1); b0[nf][1] = rdB(nf, 1, 1); }
    if (t2g < nk) stage(t2g, 1, 1, 0);
    __builtin_amdgcn_s_barrier();
    __builtin_amdgcn_s_setprio(1);
#pragma unroll
    for (int m = 0; m < 4; ++m)
#pragma unroll
      for (int nf = 0; nf < 2; ++nf) {
        acc[m][nf] = __builtin_amdgcn_mfma_f32_16x16x32_bf16(a0[m][0], b0[nf][0], acc[m][nf], 0, 0, 0);
        acc[m][nf] = __builtin_amdgcn_mfma_f32_16x16x32_bf16(a0[m][1], b0[nf][1], acc[m][nf], 0, 0, 0);
      }
    __builtin_amdgcn_s_setprio(0);
    __builtin_amdgcn_s_barrier();

    // ph6: read b1 (buf1); no stage; MFMA (M0,N1)
#pragma unroll
    for (int nf = 0; nf < 2; ++nf) { b1[nf][0] = rdB(2 + nf, 0, 1); b1[nf][1] = rdB(2 + nf, 1, 1); }
    __builtin_amdgcn_s_barrier();
    __builtin_amdgcn_s_setprio(1);
#pragma unroll
    for (int m = 0; m < 4; ++m)
#pragma unroll
      for (int nf = 0; nf < 2; ++nf) {
        acc[m][2 + nf] = __builtin_amdgcn_mfma_f32_16x16x32_bf16(a0[m][0], b1[nf][0], acc[m][2 + nf], 0, 0, 0);
        acc[m][2 + nf] = __builtin_amdgcn_mfma_f32_16x16x32_bf16(a0[m][1], b1[nf][1], acc[m][2 + nf], 0, 0, 0);
      }
    __builtin_amdgcn_s_setprio(0);
    __builtin_amdgcn_s_barrier();

    // ph7: read a1 (buf1); stage t3.B0 -> buf1 (B dead since ph6); MFMA (M1,N1)
#pragma unroll
    for (int m = 0; m < 4; ++m) { a1[m][0] = rdA(4 + m, 0, 1); a1[m][1] = rdA(4 + m, 1, 1); }
    if (t3g < nk) stage(t3g, 0, 0, 1);
    __builtin_amdgcn_s_barrier();
    __builtin_amdgcn_s_setprio(1);
#pragma unroll
    for (int m = 0; m < 4; ++m)
#pragma unroll
      for (int nf = 0; nf < 2; ++nf) {
        acc[4 + m][2 + nf] = __builtin_amdgcn_mfma_f32_16x16x32_bf16(a1[m][0], b1[nf][0], acc[4 + m][2 + nf], 0, 0, 0);
        acc[4 + m][2 + nf] = __builtin_amdgcn_mfma_f32_16x16x32_bf16(a1[m][1], b1[nf][1], acc[4 + m][2 + nf], 0, 0, 0);
      }
    __builtin_amdgcn_s_setprio(0);
    __builtin_amdgcn_s_barrier();

    // ph8: stage t3.B1 + t3.A0 (A dead since ph7); vmcnt; MFMA (M1,N0)
    if (t3g < nk) {
      stage(t3g, 0, 1, 1);
      stage(t3g, 1, 0, 1);
      asm volatile("s_waitcnt vmcnt(6)" ::: "memory");   // drains t2.A1
    } else {
      asm volatile("s_waitcnt vmcnt(0)" ::: "memory");
    }
    __builtin_amdgcn_s_barrier();
    __builtin_amdgcn_s_setprio(1);
#pragma unroll
    for (int m = 0; m < 4; ++m)
#pragma unroll
      for (int nf = 0; nf < 2; ++nf) {
        acc[4 + m][nf] = __builtin_amdgcn_mfma_f32_16x16x32_bf16(a1[m][0], b0[nf][0], acc[4 + m][nf], 0, 0, 0);
        acc[4 + m][nf] = __builtin_amdgcn_mfma_f32_16x16x32_bf16(a1[m][1], b0[nf][1], acc[4 + m][nf], 0, 0, 0);
      }
    __builtin_amdgcn_s_setprio(0);
    __builtin_amdgcn_s_barrier();
  }

  // ---- epilogue ----
  const int cc = lane & 15, qg = lane >> 4;
#pragma unroll
  for (int m = 0; m < 8; ++m) {
#pragma unroll
    for (int nf = 0; nf < 4; ++nf) {
      const int gc = col0 + wc * 64 + nf * 16 + cc;
      const float bv = bias[gc];
      const float sc = (gc < qscale_cols) ? CSCALE : 1.0f;
#pragma unroll
      for (int r = 0; r < 4; ++r) {
        const int gr = row0 + wr * 128 + m * 16 + qg * 4 + r;
        float val = (acc[m][nf][r] + bv) * sc;
        if constexpr (sizeof(OutT) == 2)
          ((u16*)C)[(size_t)gr * N + gc] = f2bf(val);
        else
          ((float*)C)[(size_t)gr * N + gc] = val;
      }
    }
  }
}

// ---------------------------------------------------------------------------
// Flash attention v6 (unchanged from R6).
// ---------------------------------------------------------------------------
__global__ __launch_bounds__(512, 4)
void attn_mfma(const u16* __restrict__ qkv, const u16* __restrict__ vT,
               u16* __restrict__ yout) {
  __shared__ int4 Ks4[512];
  __shared__ int4 Vs4[512];
  __shared__ int4 Ps4[2048];

  const int n   = blockIdx.x;
  const int xcd = n & 7, t = n >> 3;
  const int bh  = xcd * 8 + (t >> 3);
  const int ip  = t & 7;
  const int b   = bh >> 4, h = bh & 15;

  const int tid = threadIdx.x;
  const int lane = tid & 63, wq = tid >> 6;
  const int sub = wq & 3;
  const int cc = lane & 15, qg = lane >> 4;

  const int qt128 = (wq < 4) ? ip : (15 - ip);
  const int qrow0 = qt128 * 128 + sub * 32;
  const int diag  = qt128 * 2 + (sub >> 1);
  const int jn    = 32 - 2 * ip;

  const u16* kbase = qkv + (size_t)b * T_ * C3_ + C_ + h * D_;
  const u16* vtb   = vT + (size_t)bh * D_ * T_;

  bf16x8 qf[2][2];
#pragma unroll
  for (int hf = 0; hf < 2; ++hf) {
    const u16* qb = qkv + (size_t)(b * T_ + qrow0 + hf * 16 + cc) * C3_ + h * D_;
    qf[hf][0] = *(const bf16x8*)(qb + qg * 8);
    qf[hf][1] = *(const bf16x8*)(qb + 32 + qg * 8);
  }

  const u16* kg = kbase + (size_t)((tid >> 7) * 16 + (tid & 15)) * C3_ +
                  ((tid >> 6) & 1) * 32 + ((tid >> 4) & 3) * 8;
  const u16* vg = vtb + (size_t)((tid >> 7) * 16 + (tid & 15)) * T_ +
                  ((tid >> 6) & 1) * 32 + ((tid >> 4) & 3) * 8;

  int4 kpref = *(const int4*)kg;
  int4 vpref = *(const int4*)vg;

  float m_r[2] = {-1e30f, -1e30f}, l_r[2] = {0.f, 0.f};
  f32x4 o[2][4];
#pragma unroll
  for (int hf = 0; hf < 2; ++hf)
#pragma unroll
    for (int db = 0; db < 4; ++db) o[hf][db] = (f32x4){0.f, 0.f, 0.f, 0.f};

  for (int j = 0; j < jn; ++j) {
    __syncthreads();
    Ks4[tid] = kpref;
    Vs4[tid] = vpref;
    __syncthreads();
    if (j + 1 < jn) {
      kpref = *(const int4*)(kg + (size_t)(j + 1) * 64 * C3_);
      vpref = *(const int4*)(vg + (j + 1) * 64);
    }
    if (j > diag) continue;

    __builtin_amdgcn_s_setprio(1);
    f32x4 s[2][4];
#pragma unroll
    for (int kb = 0; kb < 4; ++kb) {
      bf16x8 kf0 = *(const bf16x8*)(Ks4 + kb * 128 + lane);
      bf16x8 kf1 = *(const bf16x8*)(Ks4 + kb * 128 + 64 + lane);
#pragma unroll
      for (int hf = 0; hf < 2; ++hf) {
        f32x4 z = (f32x4){0.f, 0.f, 0.f, 0.f};
        z = __builtin_amdgcn_mfma_f32_16x16x32_bf16(kf0, qf[hf][0], z, 0, 0, 0);
        z = __builtin_amdgcn_mfma_f32_16x16x32_bf16(kf1, qf[hf][1], z, 0, 0, 0);
        s[hf][kb] = z;
      }
    }
    __builtin_amdgcn_s_setprio(0);

    if (j == diag) {
#pragma unroll
      for (int hf = 0; hf < 2; ++hf) {
        const int qabs = qrow0 + hf * 16 + cc;
#pragma unroll
        for (int kb = 0; kb < 4; ++kb)
#pragma unroll
          for (int r = 0; r < 4; ++r)
            if ((j * 64 + kb * 16 + qg * 4 + r) > qabs) s[hf][kb][r] = -1e30f;
      }
    }

#pragma unroll
    for (int hf = 0; hf < 2; ++hf) {
      float mx = s[hf][0][0];
#pragma unroll
      for (int kb = 0; kb < 4; ++kb)
#pragma unroll
        for (int r = 0; r < 4; ++r) mx = fmaxf(mx, s[hf][kb][r]);
      mx = fmaxf(mx, __shfl_xor(mx, 16));
      mx = fmaxf(mx, __shfl_xor(mx, 32));

      if (!__all(mx <= m_r[hf])) {
        float mn = fmaxf(m_r[hf], mx);
        float al = exp2f(m_r[hf] - mn);
        m_r[hf] = mn;
        l_r[hf] *= al;
        float alq[4];
#pragma unroll
        for (int r = 0; r < 4; ++r)
          alq[r] = __shfl(al, (lane & 48) | (qg * 4 + r));
#pragma unroll
        for (int db = 0; db < 4; ++db)
#pragma unroll
          for (int r = 0; r < 4; ++r) o[hf][db][r] *= alq[r];
      }

      float lsum = 0.f;
#pragma unroll
      for (int kb = 0; kb < 4; ++kb)
#pragma unroll
        for (int r = 0; r < 4; ++r) {
          float p = exp2f(s[hf][kb][r] - m_r[hf]);
          s[hf][kb][r] = p;
          lsum += p;
        }
      l_r[hf] += lsum;

      char* myPb = (char*)(Ps4 + wq * 256 + hf * 128);
#pragma unroll
      for (int kb = 0; kb < 4; ++kb) {
        unsigned plo, phi;
        asm("v_cvt_pk_bf16_f32 %0, %1, %2" : "=v"(plo) : "v"(s[hf][kb][0]), "v"(s[hf][kb][1]));
        asm("v_cvt_pk_bf16_f32 %0, %1, %2" : "=v"(phi) : "v"(s[hf][kb][2]), "v"(s[hf][kb][3]));
        const int kv0 = kb * 16 + qg * 4;
        const int g = ((kv0 >> 5) << 6) + (((kv0 >> 3) & 3) << 4) + cc;
        uint2 pk; pk.x = plo; pk.y = phi;
        *(uint2*)(myPb + g * 16 + (kv0 & 7) * 2) = pk;
      }
    }

    bf16x8 pa[2][2];
#pragma unroll
    for (int hf = 0; hf < 2; ++hf)
#pragma unroll
      for (int ks = 0; ks < 2; ++ks)
        pa[hf][ks] = *(const bf16x8*)(Ps4 + wq * 256 + hf * 128 + ks * 64 + lane);
    __builtin_amdgcn_s_setprio(1);
#pragma unroll
    for (int db = 0; db < 4; ++db) {
#pragma unroll
      for (int ks = 0; ks < 2; ++ks) {
        bf16x8 vf = *(const bf16x8*)(Vs4 + db * 128 + ks * 64 + lane);
        o[0][db] = __builtin_amdgcn_mfma_f32_16x16x32_bf16(pa[0][ks], vf, o[0][db], 0, 0, 0);
        o[1][db] = __builtin_amdgcn_mfma_f32_16x16x32_bf16(pa[1][ks], vf, o[1][db], 0, 0, 0);
      }
    }
    __builtin_amdgcn_s_setprio(0);
  }

#pragma unroll
  for (int hf = 0; hf < 2; ++hf) {
    float ls = l_r[hf];
    ls += __shfl_xor(ls, 16);
    ls += __shfl_xor(ls, 32);
    float linv_l = 1.0f / ls;
    float linv[4];
#pragma unroll
    for (int r = 0; r < 4; ++r)
      linv[r] = __shfl(linv_l, (lane & 48) | (qg * 4 + r));

    u16* yb = yout + (size_t)(b * T_ + qrow0 + hf * 16 + qg * 4) * C_ + h * D_ + cc;
#pragma unroll
    for (int db = 0; db < 4; ++db)
#pragma unroll
      for (int r = 0; r < 4; ++r)
        yb[(size_t)r * C_ + db * 16] = f2bf(o[hf][db][r] * linv[r]);
  }
}

// ---------------------------------------------------------------------------
extern "C" void kernel_launch(void* const* d_in, const int* in_sizes, int n_in,
                              void* d_out, int out_size, void* d_ws, size_t ws_size,
                              hipStream_t stream) {
  const float* x      = (const float*)d_in[0];
  const float* w_attn = (const float*)d_in[1];
  const float* b_attn = (const float*)d_in[2];
  const float* w_proj = (const float*)d_in[3];
  const float* b_proj = (const float*)d_in[4];
  float* out = (float*)d_out;

  char* ws = (char*)d_ws;
  u16* xb  = (u16*)(ws);                          // 16 MB
  u16* waT = (u16*)(ws + 16777216);               //  6 MB  [3072][1024]
  u16* wpT = (u16*)(ws + 23068672);               //  2 MB  [1024][1024]
  u16* qkv = (u16*)(ws + 25165824);               // 48 MB  [8192][3072]
  u16* yb  = (u16*)(ws + 75497472);               // 16 MB  [8192][1024]
  u16* vT  = (u16*)(ws + 92274688);               // 16 MB  [64][64][2048]

  cvt_bf16<<<4096, 256, 0, stream>>>(x, xb, (B_ * T_ * C_) / 8);
  transcvt<<<dim3(C3_ / 64, C_ / 16), 256, 0, stream>>>(w_attn, waT, C_, C3_);
  transcvt<<<dim3(C_ / 64, C_ / 16), 256, 0, stream>>>(w_proj, wpT, C_, C_);

  // qkv = x @ w_attn + b_attn (q cols pre-scaled for exp2-domain softmax)
  gemm256<u16><<<dim3(C3_ / 256, (B_ * T_) / 256), 512, 0, stream>>>(
      xb, waT, b_attn, qkv, B_ * T_, C3_, C_, C_);

  vtrans<<<4096, 256, 0, stream>>>(qkv, vT);

  attn_mfma<<<dim3(8 * H_ * B_), 512, 0, stream>>>(qkv, vT, yb);

  gemm256<float><<<dim3(C_ / 256, (B_ * T_) / 256), 512, 0, stream>>>(
      yb, wpT, b_proj, out, B_ * T_, C_, C_, 0);
}